// Round 17
// baseline (1228.527 us; speedup 1.0000x reference)
//
#include <hip/hip_runtime.h>
#include <cfloat>

// ---------------------------------------------------------------------------
// GCN3D forward. Split-plane bf16 MFMA GEMMs (Dekker, f32-grade accuracy).
// Round-17: conv kernels k-split — k_conv_layer/k_conv_surface template<KG>
// distribute the 50-neighbor serial loop across KG thread groups (KG=4 @C=128,
// KG=2 @C=256/512) with exact LDS max-combine. Chain 50->13 iters, 8 waves/blk.
// B=8, N=2048->512->128, K_NB=50. Workspace ~98.0 MB.
// ---------------------------------------------------------------------------

#define BB   8
#define NP0  2048
#define NP1  512
#define NP2  128
#define KNB_ 50
#define VS0  (NP0 * 3)

typedef __attribute__((ext_vector_type(8))) short short8_t;
typedef __attribute__((ext_vector_type(4))) short short4_t;
typedef __attribute__((ext_vector_type(4))) float f32x4_t;
typedef unsigned short u16;

// ---------------- workspace layout (byte offsets) ----------------
static constexpr size_t O_V0    = 0;
static constexpr size_t O_IDX0  = 196608;
static constexpr size_t O_IDXP0 = 3473408;
static constexpr size_t O_IDX1  = 3538944;
static constexpr size_t O_IDXP1 = 4358144;
static constexpr size_t O_IDX2  = 4374528;
static constexpr size_t O_NI1   = 4579328;
static constexpr size_t O_NI2   = 4644864;
static constexpr size_t O_FGLOB = 4710400;
static constexpr size_t O_GLOB1 = 4726784;
static constexpr size_t O_COLS  = 4743168;   // mx vectors (64KB)
static constexpr size_t O_CPART = 4808704;   // inv(64KB) + csump(128KB) + v4(256KB)
static constexpr size_t O_V4    = O_CPART + 196608;
static constexpr size_t O_STATS = 5332992;
static constexpr size_t O_XCUR  = 5599232;   // 8,388,608 f32 activation scratch
static constexpr size_t O_PL    = 18182144;  // 58,855,424 plane pools
static constexpr size_t O_AREA  = 77037568;  // spart/xrp/fout/pre/xcat (phase-disjoint)
static constexpr size_t O_BPART = O_AREA + 12582912;  // 1MB bn partials

static constexpr size_t PL_WH    = 0;
static constexpr size_t PL_WL    = 4786176;
static constexpr size_t PL_FM0H  = 9572352;
static constexpr size_t PL_FM0L  = 13766656;
static constexpr size_t PL_FM1H  = 17960960;
static constexpr size_t PL_FM1L  = 22155264;
static constexpr size_t PL_FM2H  = 26349568;
static constexpr size_t PL_FM2L  = 28446720;
static constexpr size_t PL_FM3H  = 30543872;
static constexpr size_t PL_FM3L  = 32641024;
static constexpr size_t PL_FM4H  = 34738176;
static constexpr size_t PL_FM4L  = 35786752;
static constexpr size_t PL_FMP1H = 36835328;
static constexpr size_t PL_FMP1L = 37883904;
static constexpr size_t PL_FMP2H = 38932480;
static constexpr size_t PL_FMP2L = 39456768;
static constexpr size_t PL_QH    = 39981056;
static constexpr size_t PL_QL    = 41029632;
static constexpr size_t PL_VMH   = 42078208;
static constexpr size_t PL_VML   = 46272512;
static constexpr size_t PL_XSH   = 50466816;
static constexpr size_t PL_XSL   = 54661120;
static constexpr size_t PL_X1H = PL_VMH;   // head alias (vm planes dead at head)

__device__ __forceinline__ float bf2f(u16 h) {
  union { unsigned u; float f; } c; c.u = ((unsigned)h) << 16; return c.f;
}
__device__ __forceinline__ u16 f2bf(float f) {
  union { float f; unsigned u; } c; c.f = f;
  return (u16)((c.u + 0x7fffu + ((c.u >> 16) & 1u)) >> 16);
}

// ===========================================================================
// Plane GEMM. BSPLIT=false: B hi-plane only. AMODE 2: plain bf16 A.
// OUTM 4: merged q+vm epilogue.
// ===========================================================================
template <int TM, int AMODE, int BIASM, int OUTM, bool ACC, bool GIDX, bool BSPLIT = true>
__global__ __launch_bounds__(256) void k_mmp(
    const void* __restrict__ A1, const void* __restrict__ A2,
    const u16* __restrict__ Bh0, const u16* __restrict__ Bl0,
    const float* __restrict__ bias, void* __restrict__ C1, void* __restrict__ C2,
    int M, int N, int K, long sA, long sB, long sC, int ksplit,
    const int* __restrict__ gidx, long sG,
    void* __restrict__ C3, void* __restrict__ C4, int QQ, long sCv) {
  constexpr int RT = TM / 32;
  constexpr int CT = TM / 32;
  __shared__ u16 Ah[TM][40], Bh[TM][40];
  __shared__ u16 Bl[BSPLIT ? TM : 1][40];
  __shared__ u16 Al[(AMODE == 2) ? 1 : TM][40];
  const int z = blockIdx.z;
  const int zb = z / ksplit, ks = z - zb * ksplit;
  const int kchunk = K / ksplit;
  const int kl0 = ks * kchunk, kl1 = kl0 + kchunk;
  const int m0 = blockIdx.x * TM, n0 = blockIdx.y * TM;
  const int t = threadIdx.x;
  const int lane = t & 63, w = t >> 6;
  const int wr = (w >> 1) * (TM / 2), wc = (w & 1) * (TM / 2);
  const int frow = lane & 15, koff = (lane >> 4) * 8;
  f32x4_t acc[RT][CT];
#pragma unroll
  for (int i = 0; i < RT; ++i)
#pragma unroll
    for (int j = 0; j < CT; ++j) acc[i][j] = (f32x4_t){0.f, 0.f, 0.f, 0.f};

  const u16* Ahg = (const u16*)A1 + (size_t)zb * sA;
  const u16* Alg = (const u16*)A2 + (size_t)zb * sA;
  const u16* Bhg = Bh0 + (size_t)zb * sB;
  const u16* Blg = Bl0 + (size_t)zb * sB;

  int ar, ac, arow = 0;
  if constexpr (TM == 128) { ar = t >> 1; ac = (t & 1) * 16; }
  else                     { ar = t >> 2; ac = (t & 3) * 8; }
  arow = m0 + ar;
  if constexpr (GIDX) arow = (gidx + (size_t)zb * sG)[arow];
  const int bn = ar, bc = ac;
  const bool bok = (n0 + bn) < N;
  const short8_t z8 = {0, 0, 0, 0, 0, 0, 0, 0};

  for (int k0 = kl0; k0 < kl1; k0 += 32) {
    __syncthreads();
    {
      const u16* s1 = Ahg + (size_t)arow * K + k0 + ac;
      if constexpr (TM == 128) {
        *(short8_t*)&Ah[ar][ac] = *(const short8_t*)s1;
        *(short8_t*)&Ah[ar][ac + 8] = *(const short8_t*)(s1 + 8);
        if constexpr (AMODE == 0) {
          const u16* s2 = Alg + (size_t)arow * K + k0 + ac;
          *(short8_t*)&Al[ar][ac] = *(const short8_t*)s2;
          *(short8_t*)&Al[ar][ac + 8] = *(const short8_t*)(s2 + 8);
        }
      } else {
        *(short8_t*)&Ah[ar][ac] = *(const short8_t*)s1;
        if constexpr (AMODE == 0)
          *(short8_t*)&Al[ar][ac] = *(const short8_t*)(Alg + (size_t)arow * K + k0 + ac);
      }
    }
    {
      const u16* s1 = Bhg + (size_t)(n0 + bn) * K + k0 + bc;
      const u16* s2 = Blg + (size_t)(n0 + bn) * K + k0 + bc;
      if constexpr (TM == 128) {
        *(short8_t*)&Bh[bn][bc] = bok ? *(const short8_t*)s1 : z8;
        *(short8_t*)&Bh[bn][bc + 8] = bok ? *(const short8_t*)(s1 + 8) : z8;
        if constexpr (BSPLIT) {
          *(short8_t*)&Bl[bn][bc] = bok ? *(const short8_t*)s2 : z8;
          *(short8_t*)&Bl[bn][bc + 8] = bok ? *(const short8_t*)(s2 + 8) : z8;
        }
      } else {
        *(short8_t*)&Bh[bn][bc] = bok ? *(const short8_t*)s1 : z8;
        if constexpr (BSPLIT)
          *(short8_t*)&Bl[bn][bc] = bok ? *(const short8_t*)s2 : z8;
      }
    }
    __syncthreads();
    short8_t ah[RT], al[RT], bh[CT], bl[CT];
#pragma unroll
    for (int i = 0; i < RT; ++i) {
      const int r = wr + i * 16 + frow;
      ah[i] = *(const short8_t*)&Ah[r][koff];
      if constexpr (AMODE != 2) al[i] = *(const short8_t*)&Al[r][koff];
    }
#pragma unroll
    for (int i = 0; i < CT; ++i) {
      const int r = wc + i * 16 + frow;
      bh[i] = *(const short8_t*)&Bh[r][koff];
      if constexpr (BSPLIT) bl[i] = *(const short8_t*)&Bl[r][koff];
    }
#pragma unroll
    for (int i = 0; i < RT; ++i)
#pragma unroll
      for (int j = 0; j < CT; ++j) {
        acc[i][j] = __builtin_amdgcn_mfma_f32_16x16x32_bf16(ah[i], bh[j], acc[i][j], 0, 0, 0);
        if constexpr (BSPLIT)
          acc[i][j] = __builtin_amdgcn_mfma_f32_16x16x32_bf16(ah[i], bl[j], acc[i][j], 0, 0, 0);
        if constexpr (AMODE != 2)
          acc[i][j] = __builtin_amdgcn_mfma_f32_16x16x32_bf16(al[i], bh[j], acc[i][j], 0, 0, 0);
      }
  }

  const int crow = (lane >> 4) * 4;
#pragma unroll
  for (int i = 0; i < RT; ++i) {
#pragma unroll
    for (int j = 0; j < CT; ++j) {
      const int gc = n0 + wc + j * 16 + frow;
      if (gc >= N) continue;
      float bv = 0.f;
      if constexpr (BIASM == 1) bv = bias[gc];
      if constexpr (BIASM == 2) bv = bias[(size_t)zb * N + gc];
      const int gr0 = m0 + wr + i * 16 + crow;
      if constexpr (OUTM == 0) {
        float* Cp = (float*)C1 + (size_t)z * sC;
#pragma unroll
        for (int q = 0; q < 4; ++q) {
          float vv = acc[i][j][q] + bv;
          if (ACC) vv += Cp[(size_t)(gr0 + q) * N + gc];
          Cp[(size_t)(gr0 + q) * N + gc] = vv;
        }
      } else if constexpr (OUTM == 1) {
        u16* Ph = (u16*)C1 + (size_t)z * sC;
        u16* Pl = (u16*)C2 + (size_t)z * sC;
#pragma unroll
        for (int q = 0; q < 4; ++q) {
          float vv = acc[i][j][q] + bv;
          u16 h = f2bf(vv);
          Ph[(size_t)(gr0 + q) * N + gc] = h;
          Pl[(size_t)(gr0 + q) * N + gc] = f2bf(vv - bf2f(h));
        }
      } else if constexpr (OUTM == 2) {
        u16* Ph = (u16*)C1 + (size_t)z * sC;
        u16* Pl = (u16*)C2 + (size_t)z * sC;
        short4_t h4, l4;
#pragma unroll
        for (int q = 0; q < 4; ++q) {
          float vv = acc[i][j][q] + bv;
          u16 h = f2bf(vv);
          h4[q] = (short)h;
          l4[q] = (short)f2bf(vv - bf2f(h));
        }
        *(short4_t*)(Ph + (size_t)gc * M + gr0) = h4;
        *(short4_t*)(Pl + (size_t)gc * M + gr0) = l4;
      } else if constexpr (OUTM == 4) {
        if (gc < QQ) {
          u16* Ph = (u16*)C1 + (size_t)zb * sC;
          u16* Pl = (u16*)C2 + (size_t)zb * sC;
#pragma unroll
          for (int q = 0; q < 4; ++q) {
            float vv = acc[i][j][q];
            u16 h = f2bf(vv);
            Ph[(size_t)(gr0 + q) * QQ + gc] = h;
            Pl[(size_t)(gr0 + q) * QQ + gc] = f2bf(vv - bf2f(h));
          }
        } else {
          const int cv = gc - QQ;
          const float bv2 = bias[cv];
          u16* Th = (u16*)C3 + (size_t)zb * sCv;
          u16* Tl = (u16*)C4 + (size_t)zb * sCv;
          short4_t h4, l4;
#pragma unroll
          for (int q = 0; q < 4; ++q) {
            float vv = acc[i][j][q] + bv2;
            u16 h = f2bf(vv);
            h4[q] = (short)h;
            l4[q] = (short)f2bf(vv - bf2f(h));
          }
          *(short4_t*)(Th + (size_t)cv * M + gr0) = h4;
          *(short4_t*)(Tl + (size_t)cv * M + gr0) = l4;
        }
      } else {  // OUTM 3: relu -> plain bf16
        u16* Cb = (u16*)C1 + (size_t)z * sC;
#pragma unroll
        for (int q = 0; q < 4; ++q) {
          float vv = fmaxf(acc[i][j][q] + bv, 0.f);
          Cb[(size_t)(gr0 + q) * N + gc] = f2bf(vv);
        }
      }
    }
  }
}

template <int TM, int AMODE, int BIASM, int OUTM, bool ACC, bool GIDX, bool BSPLIT = true>
static void mmp(hipStream_t st, const void* A1, const void* A2,
                const u16* Bh, const u16* Bl, const float* bias,
                void* C1, void* C2, int M, int N, int K,
                long sA, long sB, long sC, int Z, int ksplit,
                const int* gidx = nullptr, long sG = 0,
                void* C3 = nullptr, void* C4 = nullptr, int QQ = 0, long sCv = 0) {
  dim3 grid(M / TM, (N + TM - 1) / TM, Z * ksplit);
  k_mmp<TM, AMODE, BIASM, OUTM, ACC, GIDX, BSPLIT><<<grid, 256, 0, st>>>(
      A1, A2, Bh, Bl, bias, C1, C2, M, N, K, sA, sB, sC, ksplit, gidx, sG,
      C3, C4, QQ, sCv);
}

// ===========================================================================
// Fused attention. stats NSPLIT partials + merge; xr NSPLIT.
// ===========================================================================
template <int QD, int NS>
__global__ __launch_bounds__(256) void k_sa_stats(
    const u16* __restrict__ qh, const u16* __restrict__ ql, int N,
    float* __restrict__ mx, float* __restrict__ inv,
    float* __restrict__ Mp, float* __restrict__ Sp) {
  __shared__ float mr[2][64], sr[2][64];
  const int b = blockIdx.y;
  const int m0 = blockIdx.x * 64;
  const int sidx = blockIdx.z;
  const int t = threadIdx.x, lane = t & 63, w = t >> 6;
  const int wm = (w >> 1) * 32, wn = (w & 1) * 64;
  const int frow = lane & 15, kq = (lane >> 4) * 8;
  const u16* qhb = qh + (size_t)b * N * QD;
  const u16* qlb = ql + (size_t)b * N * QD;
  constexpr int KS = QD / 32;
  short8_t ahq[KS][2], alq[KS][2];
#pragma unroll
  for (int ks = 0; ks < KS; ++ks)
#pragma unroll
    for (int i = 0; i < 2; ++i) {
      const size_t r = (size_t)(m0 + wm + i * 16 + frow) * QD + ks * 32 + kq;
      ahq[ks][i] = *(const short8_t*)(qhb + r);
      alq[ks][i] = *(const short8_t*)(qlb + r);
    }
  float M[2][4], S[2][4];
#pragma unroll
  for (int i = 0; i < 2; ++i)
#pragma unroll
    for (int q = 0; q < 4; ++q) { M[i][q] = -FLT_MAX; S[i][q] = 0.f; }

  const int nlo = sidx * (N / NS), nhi = nlo + N / NS;
  for (int n0 = nlo; n0 < nhi; n0 += 128) {
    f32x4_t acc[2][4];
#pragma unroll
    for (int i = 0; i < 2; ++i)
#pragma unroll
      for (int j = 0; j < 4; ++j) acc[i][j] = (f32x4_t){0.f, 0.f, 0.f, 0.f};
#pragma unroll
    for (int ks = 0; ks < KS; ++ks) {
      short8_t b_h[4], b_l[4];
#pragma unroll
      for (int j = 0; j < 4; ++j) {
        const size_t r = (size_t)(n0 + wn + j * 16 + frow) * QD + ks * 32 + kq;
        b_h[j] = *(const short8_t*)(qhb + r);
        b_l[j] = *(const short8_t*)(qlb + r);
      }
#pragma unroll
      for (int i = 0; i < 2; ++i)
#pragma unroll
        for (int j = 0; j < 4; ++j) {
          acc[i][j] = __builtin_amdgcn_mfma_f32_16x16x32_bf16(ahq[ks][i], b_h[j], acc[i][j], 0, 0, 0);
          acc[i][j] = __builtin_amdgcn_mfma_f32_16x16x32_bf16(ahq[ks][i], b_l[j], acc[i][j], 0, 0, 0);
          acc[i][j] = __builtin_amdgcn_mfma_f32_16x16x32_bf16(alq[ks][i], b_h[j], acc[i][j], 0, 0, 0);
        }
    }
#pragma unroll
    for (int i = 0; i < 2; ++i)
#pragma unroll
      for (int q = 0; q < 4; ++q) {
        float tm = acc[i][0][q];
#pragma unroll
        for (int j = 1; j < 4; ++j) tm = fmaxf(tm, acc[i][j][q]);
#pragma unroll
        for (int off = 1; off < 16; off <<= 1) tm = fmaxf(tm, __shfl_xor(tm, off));
        const float Mn = fmaxf(M[i][q], tm);
        float ps = 0.f;
#pragma unroll
        for (int j = 0; j < 4; ++j) ps += __expf(acc[i][j][q] - Mn);
#pragma unroll
        for (int off = 1; off < 16; off <<= 1) ps += __shfl_xor(ps, off);
        S[i][q] = S[i][q] * __expf(M[i][q] - Mn) + ps;
        M[i][q] = Mn;
      }
  }
  if (frow == 0) {
#pragma unroll
    for (int i = 0; i < 2; ++i)
#pragma unroll
      for (int q = 0; q < 4; ++q) {
        const int ml = wm + i * 16 + (lane >> 4) * 4 + q;
        mr[w & 1][ml] = M[i][q];
        sr[w & 1][ml] = S[i][q];
      }
  }
  __syncthreads();
  if (t < 64) {
    const float M0 = mr[0][t], M1 = mr[1][t];
    const float Mm = fmaxf(M0, M1);
    const float Sm = sr[0][t] * __expf(M0 - Mm) + sr[1][t] * __expf(M1 - Mm);
    if constexpr (NS == 1) {
      mx[(size_t)b * N + m0 + t] = Mm;
      inv[(size_t)b * N + m0 + t] = 1.f / Sm;
    } else {
      const size_t o = ((size_t)sidx * BB + b) * N + m0 + t;
      Mp[o] = Mm;
      Sp[o] = Sm;
    }
  }
}

template <int NS>
__global__ void k_smerge(const float* __restrict__ Mp, const float* __restrict__ Sp,
                         float* __restrict__ mx, float* __restrict__ inv, int total) {
  int i = blockIdx.x * 256 + threadIdx.x;
  if (i >= total) return;
  float M = -FLT_MAX;
#pragma unroll
  for (int s = 0; s < NS; ++s) M = fmaxf(M, Mp[(size_t)s * total + i]);
  float S = 0.f;
#pragma unroll
  for (int s = 0; s < NS; ++s)
    S += Sp[(size_t)s * total + i] * __expf(Mp[(size_t)s * total + i] - M);
  mx[i] = M;
  inv[i] = 1.f / S;
}

template <int QD, int NSPLIT>
__global__ __launch_bounds__(256) void k_sa_xr(
    const u16* __restrict__ qh, const u16* __restrict__ ql,
    const u16* __restrict__ vmh, const u16* __restrict__ vml,
    const float* __restrict__ mx, const float* __restrict__ inv,
    const float* __restrict__ xcur, u16* __restrict__ xsh, u16* __restrict__ xsl,
    float* __restrict__ xrp, float* __restrict__ csump,
    int N, int C) {
  __shared__ __align__(16) u16 Ph[64][132];
  __shared__ __align__(16) u16 Vh[128][68], Vl[128][68];
  const int b = blockIdx.z / NSPLIT, sidx = blockIdx.z % NSPLIT;
  const int m0 = blockIdx.x * 64, c0 = blockIdx.y * 128;
  const int t = threadIdx.x, lane = t & 63, w = t >> 6;
  const int wm = (w >> 1) * 32, wn = (w & 1) * 64;
  const int frow = lane & 15, kq = (lane >> 4) * 8;
  const u16* qhb = qh + (size_t)b * N * QD;
  const u16* qlb = ql + (size_t)b * N * QD;
  const u16* vhb = vmh + (size_t)b * (size_t)N * C;
  const u16* vlb = vml + (size_t)b * (size_t)N * C;
  const float* mxb = mx + (size_t)b * N;
  const float* invb = inv + (size_t)b * N;
  constexpr int KS = QD / 32;
  const int vr = t >> 1, vco = (t & 1) * 32;
  short8_t ahq[KS][2], alq[KS][2];
#pragma unroll
  for (int ks = 0; ks < KS; ++ks)
#pragma unroll
    for (int i = 0; i < 2; ++i) {
      const size_t r = (size_t)(m0 + wm + i * 16 + frow) * QD + ks * 32 + kq;
      ahq[ks][i] = *(const short8_t*)(qhb + r);
      alq[ks][i] = *(const short8_t*)(qlb + r);
    }
  f32x4_t xacc[2][4];
  float csum[2][4];
#pragma unroll
  for (int i = 0; i < 2; ++i)
#pragma unroll
    for (int j = 0; j < 4; ++j) { xacc[i][j] = (f32x4_t){0.f, 0.f, 0.f, 0.f}; csum[i][j] = 0.f; }

  const int nlo = sidx * (N / NSPLIT), nhi = nlo + N / NSPLIT;
  for (int n0 = nlo; n0 < nhi; n0 += 128) {
    __syncthreads();
    {
      const u16* s1 = vhb + (size_t)(c0 + vr) * N + n0 + vco;
      const u16* s2 = vlb + (size_t)(c0 + vr) * N + n0 + vco;
#pragma unroll
      for (int u = 0; u < 4; ++u) {
        *(short8_t*)&Vh[vr][vco + u * 8] = *(const short8_t*)(s1 + u * 8);
        *(short8_t*)&Vl[vr][vco + u * 8] = *(const short8_t*)(s2 + u * 8);
      }
    }
    f32x4_t acc[2][4];
#pragma unroll
    for (int i = 0; i < 2; ++i)
#pragma unroll
      for (int j = 0; j < 4; ++j) acc[i][j] = (f32x4_t){0.f, 0.f, 0.f, 0.f};
#pragma unroll
    for (int ks = 0; ks < KS; ++ks) {
      short8_t b_h[4], b_l[4];
#pragma unroll
      for (int j = 0; j < 4; ++j) {
        const size_t r = (size_t)(n0 + wn + j * 16 + frow) * QD + ks * 32 + kq;
        b_h[j] = *(const short8_t*)(qhb + r);
        b_l[j] = *(const short8_t*)(qlb + r);
      }
#pragma unroll
      for (int i = 0; i < 2; ++i)
#pragma unroll
        for (int j = 0; j < 4; ++j) {
          acc[i][j] = __builtin_amdgcn_mfma_f32_16x16x32_bf16(ahq[ks][i], b_h[j], acc[i][j], 0, 0, 0);
          acc[i][j] = __builtin_amdgcn_mfma_f32_16x16x32_bf16(ahq[ks][i], b_l[j], acc[i][j], 0, 0, 0);
          acc[i][j] = __builtin_amdgcn_mfma_f32_16x16x32_bf16(alq[ks][i], b_h[j], acc[i][j], 0, 0, 0);
        }
    }
    float mxj[4], ivj[4];
#pragma unroll
    for (int j = 0; j < 4; ++j) {
      const int n = n0 + wn + j * 16 + frow;
      mxj[j] = mxb[n];
      ivj[j] = invb[n];
    }
    const int mbase = wm + (lane >> 4) * 4;
#pragma unroll
    for (int i = 0; i < 2; ++i)
#pragma unroll
      for (int j = 0; j < 4; ++j)
#pragma unroll
        for (int q = 0; q < 4; ++q) {
          const float pv = __expf(acc[i][j][q] - mxj[j]) * ivj[j];
          csum[i][q] += pv;
          Ph[mbase + i * 16 + q][wn + j * 16 + frow] = f2bf(pv);
        }
    __syncthreads();
#pragma unroll
    for (int ks2 = 0; ks2 < 2; ++ks2) {
      short8_t p_h[2], v_h[4], v_l[4];
#pragma unroll
      for (int i = 0; i < 2; ++i)
        p_h[i] = *(const short8_t*)&Ph[wm + i * 16 + frow][ks2 * 32 + kq];
#pragma unroll
      for (int j = 0; j < 4; ++j) {
        v_h[j] = *(const short8_t*)&Vh[wn + j * 16 + frow][ks2 * 32 + kq];
        v_l[j] = *(const short8_t*)&Vl[wn + j * 16 + frow][ks2 * 32 + kq];
      }
#pragma unroll
      for (int i = 0; i < 2; ++i)
#pragma unroll
        for (int j = 0; j < 4; ++j) {
          xacc[i][j] = __builtin_amdgcn_mfma_f32_16x16x32_bf16(p_h[i], v_h[j], xacc[i][j], 0, 0, 0);
          xacc[i][j] = __builtin_amdgcn_mfma_f32_16x16x32_bf16(p_h[i], v_l[j], xacc[i][j], 0, 0, 0);
        }
    }
    __syncthreads();
    {
      const u16* s1 = vhb + (size_t)(c0 + vr) * N + n0 + 64 + vco;
      const u16* s2 = vlb + (size_t)(c0 + vr) * N + n0 + 64 + vco;
#pragma unroll
      for (int u = 0; u < 4; ++u) {
        *(short8_t*)&Vh[vr][vco + u * 8] = *(const short8_t*)(s1 + u * 8);
        *(short8_t*)&Vl[vr][vco + u * 8] = *(const short8_t*)(s2 + u * 8);
      }
    }
    __syncthreads();
#pragma unroll
    for (int ks2 = 0; ks2 < 2; ++ks2) {
      short8_t p_h[2], v_h[4], v_l[4];
#pragma unroll
      for (int i = 0; i < 2; ++i)
        p_h[i] = *(const short8_t*)&Ph[wm + i * 16 + frow][64 + ks2 * 32 + kq];
#pragma unroll
      for (int j = 0; j < 4; ++j) {
        v_h[j] = *(const short8_t*)&Vh[wn + j * 16 + frow][ks2 * 32 + kq];
        v_l[j] = *(const short8_t*)&Vl[wn + j * 16 + frow][ks2 * 32 + kq];
      }
#pragma unroll
      for (int i = 0; i < 2; ++i)
#pragma unroll
        for (int j = 0; j < 4; ++j) {
          xacc[i][j] = __builtin_amdgcn_mfma_f32_16x16x32_bf16(p_h[i], v_h[j], xacc[i][j], 0, 0, 0);
          xacc[i][j] = __builtin_amdgcn_mfma_f32_16x16x32_bf16(p_h[i], v_l[j], xacc[i][j], 0, 0, 0);
        }
    }
  }
#pragma unroll
  for (int i = 0; i < 2; ++i)
#pragma unroll
    for (int q = 0; q < 4; ++q)
#pragma unroll
      for (int off = 1; off < 16; off <<= 1) csum[i][q] += __shfl_xor(csum[i][q], off);
  __syncthreads();
  float* csb = (float*)&Ph[0][0];
  if (frow == 0) {
#pragma unroll
    for (int i = 0; i < 2; ++i)
#pragma unroll
      for (int q = 0; q < 4; ++q)
        csb[(w & 1) * 64 + wm + i * 16 + (lane >> 4) * 4 + q] = csum[i][q];
  }
  __syncthreads();
  if (t < 64) csb[128 + t] = csb[t] + csb[64 + t];
  __syncthreads();
  if constexpr (NSPLIT > 1) {
    if (t < 64 && blockIdx.y == 0)
      csump[((size_t)sidx * BB + b) * N + m0 + t] = csb[128 + t];
    float* xp = xrp + (size_t)sidx * BB * N * C;
#pragma unroll
    for (int i = 0; i < 2; ++i)
#pragma unroll
      for (int q = 0; q < 4; ++q) {
        const int mloc = wm + i * 16 + (lane >> 4) * 4 + q;
        const size_t rowoff = ((size_t)b * N + m0 + mloc) * C;
#pragma unroll
        for (int j = 0; j < 4; ++j)
          xp[rowoff + c0 + wn + j * 16 + frow] = xacc[i][j][q];
      }
  } else {
#pragma unroll
    for (int i = 0; i < 2; ++i) {
#pragma unroll
      for (int q = 0; q < 4; ++q) {
        const int mloc = wm + i * 16 + (lane >> 4) * 4 + q;
        const float cstot = csb[128 + mloc];
        const size_t rowoff = ((size_t)b * N + m0 + mloc) * C;
#pragma unroll
        for (int j = 0; j < 4; ++j) {
          const int gc = c0 + wn + j * 16 + frow;
          const float val = xcur[rowoff + gc] - xacc[i][j][q] / (1e-9f + cstot);
          const u16 h = f2bf(val);
          xsh[rowoff + gc] = h;
          xsl[rowoff + gc] = f2bf(val - bf2f(h));
        }
      }
    }
  }
}

template <int NS>
__global__ void k_xsub2(const float* __restrict__ xrp, const float* __restrict__ csump,
                        const float* __restrict__ xcur, u16* __restrict__ xsh,
                        u16* __restrict__ xsl, int N, int C) {
  const size_t total = (size_t)BB * N * C;
  size_t i = (size_t)blockIdx.x * 256 + threadIdx.x;
  if (i >= total) return;
  const size_t row = i / C;
  float s = 0.f, cs = 0.f;
#pragma unroll
  for (int k = 0; k < NS; ++k) {
    s += xrp[(size_t)k * total + i];
    cs += csump[(size_t)k * BB * N + row];
  }
  const float val = xcur[i] - s / (1e-9f + cs);
  const u16 h = f2bf(val);
  xsh[i] = h;
  xsl[i] = f2bf(val - bf2f(h));
}

// ===========================================================================
// weight split + activation split + head gather
// ===========================================================================
struct SplitJob { const float* s; u16* dh; u16* dl; int n, K, N, trans; };
struct SplitJobs { SplitJob j[22]; };
__global__ void k_splitjobs(SplitJobs jobs) {
  SplitJob jb = jobs.j[blockIdx.y];
  for (int i = blockIdx.x * 256 + threadIdx.x; i < jb.n; i += gridDim.x * 256) {
    float v;
    if (jb.trans) { int k = i % jb.K, n = i / jb.K; v = jb.s[(size_t)k * jb.N + n]; }
    else v = jb.s[i];
    u16 h = f2bf(v);
    jb.dh[i] = h;
    jb.dl[i] = f2bf(v - bf2f(h));
  }
}

template <bool RELU, bool LO>
__global__ void k_split4(const float* __restrict__ x, u16* __restrict__ ph,
                         u16* __restrict__ pl, int n4) {
  int i = blockIdx.x * 256 + threadIdx.x;
  if (i >= n4) return;
  float4 v = ((const float4*)x)[i];
  short4_t h4, l4;
  float vv[4] = {v.x, v.y, v.z, v.w};
#pragma unroll
  for (int q = 0; q < 4; ++q) {
    float f = RELU ? fmaxf(vv[q], 0.f) : vv[q];
    u16 h = f2bf(f);
    h4[q] = (short)h;
    if (LO) l4[q] = (short)f2bf(f - bf2f(h));
  }
  *(short4_t*)(ph + (size_t)i * 4) = h4;
  if (LO) *(short4_t*)(pl + (size_t)i * 4) = l4;
}

__global__ void k_xcat(const u16* __restrict__ f0, const u16* __restrict__ f1,
                       const u16* __restrict__ f2, const u16* __restrict__ f3,
                       const u16* __restrict__ f4, const int* __restrict__ ni1,
                       const int* __restrict__ ni2, u16* __restrict__ xcat, int b0) {
  const int G = 1280 / 8;
  int i = blockIdx.x * 256 + threadIdx.x;
  if (i >= 4 * NP0 * G) return;
  const int g = i % G, n = (i / G) % NP0, bl = i / (G * NP0);
  const int b = b0 + bl;
  const int k = g * 8;
  short8_t v;
  if (k < 128)      v = *(const short8_t*)(f0 + ((size_t)b * NP0 + n) * 128 + k);
  else if (k < 256) v = *(const short8_t*)(f1 + ((size_t)b * NP0 + n) * 128 + (k - 128));
  else if (k < 512) v = *(const short8_t*)(f2 + ((size_t)b * NP1 + ni1[b * NP0 + n]) * 256 + (k - 256));
  else if (k < 768) v = *(const short8_t*)(f3 + ((size_t)b * NP1 + ni1[b * NP0 + n]) * 256 + (k - 512));
  else              v = *(const short8_t*)(f4 + ((size_t)b * NP2 + ni2[b * NP0 + n]) * 512 + (k - 768));
  *(short8_t*)(xcat + ((size_t)bl * NP0 + n) * 1280 + k) = v;
}

// ===========================================================================
// KNN — LDS-free, early-exit radix descent (exact set).
// ===========================================================================
template <int NCAND, int KSEL>
__global__ __launch_bounds__(256) void k_knn_radix(const float4* __restrict__ v4,
                                                   int Nq, int* __restrict__ outIdx) {
  const int b = blockIdx.y;
  const int wave = threadIdx.x >> 6, lane = threadIdx.x & 63;
  const int qi = blockIdx.x * 4 + wave;
  const float4* vb4 = v4 + (size_t)b * NP0;
  const float4 qp = vb4[qi];
  constexpr int CH = NCAND / 64;
  unsigned d[CH];
  unsigned x[32];
#pragma unroll
  for (int j = 0; j < 32; ++j) x[j] = 0u;
#pragma unroll
  for (int j = 0; j < CH; ++j) {
    const int m = lane + j * 64;
    const float4 cp = vb4[m];
    const float dx = cp.x - qp.x, dy = cp.y - qp.y, dz = cp.z - qp.z;
    const float dd = dx * dx + dy * dy + dz * dz;
    d[j] = __float_as_uint((m == qi) ? FLT_MAX : dd);
    x[j] = d[j];
  }
#pragma unroll
  for (int st = 0; st < 5; ++st) {
    const int s = 16 >> st;
    const unsigned ml = (s == 16) ? 0x0000FFFFu : (s == 8) ? 0x00FF00FFu
                      : (s == 4) ? 0x0F0F0F0Fu : (s == 2) ? 0x33333333u : 0x55555555u;
#pragma unroll
    for (int i = 0; i < 32; ++i) {
      if (i & s) continue;
      unsigned t = ((x[i] >> s) ^ x[i + s]) & ml;
      x[i + s] ^= t;
      x[i] ^= (t << s);
    }
  }
  unsigned active = (CH == 32) ? 0xFFFFFFFFu : ((1u << CH) - 1u);
  unsigned T = 0u;
  int kk = KSEL;
  int actcnt = NCAND;
  bool done = false;
#pragma unroll 1
  for (int bb = 30; bb >= 2; bb -= 2) {
    const unsigned mh = x[bb], mlo = x[bb - 1];
    const unsigned a00 = active & ~mh & ~mlo;
    const unsigned a01 = active & ~mh & mlo;
    const unsigned a10 = active & mh & ~mlo;
    unsigned pA = (unsigned)__popc(a00) | ((unsigned)__popc(a01) << 16);
    unsigned pB = (unsigned)__popc(a10);
#pragma unroll
    for (int off = 32; off; off >>= 1) {
      pA += __shfl_xor(pA, off);
      pB += __shfl_xor(pB, off);
    }
    const int C00 = (int)(pA & 0xFFFFu), C01 = (int)(pA >> 16), C10 = (int)pB;
    if (kk <= C00) {
      active = a00; actcnt = C00;
    } else if (kk <= C00 + C01) {
      kk -= C00; active = a01; actcnt = C01; T |= 1u << (bb - 1);
    } else if (kk <= C00 + C01 + C10) {
      kk -= C00 + C01; active = a10; actcnt = C10; T |= 1u << bb;
    } else {
      kk -= C00 + C01 + C10;
      active = active & mh & mlo;
      actcnt = actcnt - C00 - C01 - C10;
      T |= 3u << (bb - 1);
    }
    if (actcnt == kk) { done = true; break; }  // entire active set selected
  }
  if (!done) {
    const unsigned zn = active & ~x[0];
    int c0 = __popc(zn);
#pragma unroll
    for (int off = 32; off; off >>= 1) c0 += __shfl_xor(c0, off);
    if (kk <= c0) active = zn;
    else { active &= x[0]; T |= 1u; }
  }
  int* orow = outIdx + ((size_t)b * Nq + qi) * KSEL;
  const unsigned long long ltmask = (1ull << lane) - 1ull;
  int base = 0;
#pragma unroll
  for (int j = 0; j < CH; ++j) {
    const bool sel = d[j] < T;
    const unsigned long long bal = __ballot(sel);
    const int pos = base + (int)__popcll(bal & ltmask);
    if (sel) orow[pos] = lane + j * 64;
    base += (int)__popcll(bal);
  }
  for (int j = 0; j < CH; ++j) {
    if (base >= KSEL) break;
    const bool sel = ((active >> j) & 1u) != 0u;
    const unsigned long long bal = __ballot(sel);
    const int pos = base + (int)__popcll(bal & ltmask);
    if (sel && pos < KSEL) orow[pos] = lane + j * 64;
    base += (int)__popcll(bal);
  }
}

template <int NCAND, int KSEL>
__global__ __launch_bounds__(256) void k_knn2(const float4* __restrict__ v4,
                                              int Nq, int* __restrict__ outIdx) {
  const int b = blockIdx.y;
  const int wave = threadIdx.x >> 6, lane = threadIdx.x & 63;
  const int qi = blockIdx.x * 4 + wave;
  const float4* vb4 = v4 + (size_t)b * NP0;
  const float4 qp = vb4[qi];
  constexpr int CH = NCAND / 64;
  float d[CH];
#pragma unroll
  for (int j = 0; j < CH; ++j) {
    const int m = lane + j * 64;
    const float4 cp = vb4[m];
    const float dx = cp.x - qp.x, dy = cp.y - qp.y, dz = cp.z - qp.z;
    const float dd = dx * dx + dy * dy + dz * dz;
    d[j] = (m == qi) ? FLT_MAX : dd;
  }
  int* orow = outIdx + ((size_t)b * Nq + qi) * KSEL;
#pragma unroll 1
  for (int s = 0; s < KSEL; ++s) {
    float bd = FLT_MAX; int bj = 0;
#pragma unroll
    for (int j = 0; j < CH; ++j) {
      const bool better = d[j] < bd;
      bd = better ? d[j] : bd;
      bj = better ? j : bj;
    }
    int bm = lane + bj * 64;
#pragma unroll
    for (int off = 32; off; off >>= 1) {
      const float od = __shfl_xor(bd, off);
      const int om = __shfl_xor(bm, off);
      if (od < bd || (od == bd && om < bm)) { bd = od; bm = om; }
    }
    if (lane == 0) orow[s] = bm;
#pragma unroll
    for (int j = 0; j < CH; ++j)
      if (bm == lane + j * 64) d[j] = FLT_MAX;
  }
}

__global__ void k_transpose(const float* __restrict__ in, float* __restrict__ out,
                            float* __restrict__ out4) {
  int i = blockIdx.x * 256 + threadIdx.x;
  if (i >= BB * NP0 * 3) return;
  int dd = i % 3, tt = (i / 3) % NP0, b = i / (3 * NP0);
  float v = in[((size_t)b * 3 + dd) * NP0 + tt];
  out[i] = v;
  out4[((size_t)b * NP0 + tt) * 4 + dd] = v;
}

// KG thread-groups split the 50-neighbor loop; exact LDS max-combine.
template <int KG>
__global__ void k_conv_surface(const float* __restrict__ v, const int* __restrict__ idx,
                               const float* __restrict__ dirs, float* __restrict__ out,
                               int N, int M) {
  __shared__ float su[KNB_ * 3];
  __shared__ float red[(KG > 1) ? (KG - 1) * 512 : 1];
  int b = blockIdx.y, n = blockIdx.x, t = threadIdx.x;
  const int g = t / M, c = t - g * M;
  const float* vb = v + (size_t)b * VS0;
  float cx = vb[n * 3], cy = vb[n * 3 + 1], cz = vb[n * 3 + 2];
  const int* irow = idx + ((size_t)b * N + n) * KNB_;
  if (t < KNB_) {
    int j = irow[t];
    float dx = vb[j * 3] - cx, dy = vb[j * 3 + 1] - cy, dz = vb[j * 3 + 2] - cz;
    float inv = 1.f / fmaxf(sqrtf(dx * dx + dy * dy + dz * dz), 1e-12f);
    su[t * 3] = dx * inv; su[t * 3 + 1] = dy * inv; su[t * 3 + 2] = dz * inv;
  }
  __syncthreads();
  float d0 = dirs[c], d1 = dirs[M + c], d2 = dirs[2 * M + c];
  float inv = 1.f / fmaxf(sqrtf(d0 * d0 + d1 * d1 + d2 * d2), 1e-12f);
  d0 *= inv; d1 *= inv; d2 *= inv;
  constexpr int KH = (KNB_ + KG - 1) / KG;
  const int k0 = g * KH, k1 = (k0 + KH < KNB_) ? k0 + KH : KNB_;
  float acc = 0.f;
  for (int k = k0; k < k1; ++k) {
    float th = fmaxf(su[k * 3] * d0 + su[k * 3 + 1] * d1 + su[k * 3 + 2] * d2, 0.f);
    acc = fmaxf(acc, th);
  }
  if constexpr (KG > 1) {
    if (g > 0) red[(g - 1) * M + c] = acc;
    __syncthreads();
    if (g == 0) {
#pragma unroll
      for (int gg = 1; gg < KG; ++gg) acc = fmaxf(acc, red[(gg - 1) * M + c]);
      out[((size_t)b * N + n) * M + c] = acc;
    }
  } else {
    out[((size_t)b * N + n) * M + c] = acc;
  }
}

template <int KG>
__global__ void k_conv_layer(const float* __restrict__ v, const int* __restrict__ idx,
                             const float* __restrict__ dirs, const float* __restrict__ fout,
                             float* __restrict__ out, int N, int C) {
  __shared__ float su[KNB_ * 3];
  __shared__ int sidx[KNB_];
  __shared__ float red[(KG > 1) ? (KG - 1) * 512 : 1];
  int b = blockIdx.y, n = blockIdx.x, t = threadIdx.x;
  const int g = t / C, c = t - g * C;
  const float* vb = v + (size_t)b * VS0;
  float cx = vb[n * 3], cy = vb[n * 3 + 1], cz = vb[n * 3 + 2];
  const int* irow = idx + ((size_t)b * N + n) * KNB_;
  if (t < KNB_) {
    int j = irow[t]; sidx[t] = j;
    float dx = vb[j * 3] - cx, dy = vb[j * 3 + 1] - cy, dz = vb[j * 3 + 2] - cz;
    float inv = 1.f / fmaxf(sqrtf(dx * dx + dy * dy + dz * dz), 1e-12f);
    su[t * 3] = dx * inv; su[t * 3 + 1] = dy * inv; su[t * 3 + 2] = dz * inv;
  }
  __syncthreads();
  float d0 = dirs[c], d1 = dirs[C + c], d2 = dirs[2 * C + c];
  float inv = 1.f / fmaxf(sqrtf(d0 * d0 + d1 * d1 + d2 * d2), 1e-12f);
  d0 *= inv; d1 *= inv; d2 *= inv;
  const float* fb = fout + (size_t)b * N * 2 * C;
  constexpr int KH = (KNB_ + KG - 1) / KG;
  const int k0 = g * KH, k1 = (k0 + KH < KNB_) ? k0 + KH : KNB_;
  float acc = -FLT_MAX;
  for (int k = k0; k < k1; ++k) {
    float th = fmaxf(su[k * 3] * d0 + su[k * 3 + 1] * d1 + su[k * 3 + 2] * d2, 0.f);
    float fs = fb[(size_t)sidx[k] * 2 * C + C + c];
    acc = fmaxf(acc, th * fs);
  }
  if constexpr (KG > 1) {
    if (g > 0) red[(g - 1) * C + c] = acc;
    __syncthreads();
    if (g == 0) {
#pragma unroll
      for (int gg = 1; gg < KG; ++gg) acc = fmaxf(acc, red[(gg - 1) * C + c]);
      out[((size_t)b * N + n) * C + c] = fb[(size_t)n * 2 * C + c] + acc;
    }
  } else {
    out[((size_t)b * N + n) * C + c] = fb[(size_t)n * 2 * C + c] + acc;
  }
}

// ===========================================================================
// BN / pool / misc
// ===========================================================================
__global__ void k_bn_part(const float* __restrict__ x, int rows, int C, float* __restrict__ part) {
  const int blk = blockIdx.x;
  const int chunk = rows / 256;
  const int r0 = blk * chunk;
  const int c0 = threadIdx.x, c1 = threadIdx.x + 256;
  float s0 = 0, s20 = 0, s1 = 0, s21 = 0;
  for (int r = 0; r < chunk; ++r) {
    const float* row = x + (size_t)(r0 + r) * C;
    if (c0 < C) { float v = row[c0]; s0 += v; s20 += v * v; }
    if (c1 < C) { float v = row[c1]; s1 += v; s21 += v * v; }
  }
  float* p = part + (size_t)blk * 1024;
  if (c0 < C) { p[c0] = s0; p[512 + c0] = s20; }
  if (c1 < C) { p[c1] = s1; p[512 + c1] = s21; }
}

__global__ void k_bn_fin(const float* __restrict__ part, int rows, int C, float* __restrict__ stats) {
  __shared__ float sm0[8][32], sm1[8][32];
  const int cl = threadIdx.x & 31, ch = threadIdx.x >> 5;
  const int c = blockIdx.x * 32 + cl;
  float s = 0, s2 = 0;
  if (c < C) {
    for (int b2 = ch * 32; b2 < ch * 32 + 32; ++b2) {
      s += part[b2 * 1024 + c];
      s2 += part[b2 * 1024 + 512 + c];
    }
  }
  sm0[ch][cl] = s; sm1[ch][cl] = s2;
  __syncthreads();
  if (ch == 0 && c < C) {
    float S = 0, S2 = 0;
#pragma unroll
    for (int k = 0; k < 8; ++k) { S += sm0[k][cl]; S2 += sm1[k][cl]; }
    float m = S / rows;
    float var = S2 / rows - m * m;
    stats[c] = m;
    stats[C + c] = rsqrtf(var + 1e-5f);
  }
}

template <bool ADD>
__global__ void k_bn_apply(const float* __restrict__ x, const float* __restrict__ stats,
                           const float* __restrict__ g, const float* __restrict__ bb,
                           const float* __restrict__ base, float* __restrict__ outf,
                           u16* __restrict__ ph, u16* __restrict__ pl, int total, int C) {
  int i = blockIdx.x * 256 + threadIdx.x;
  if (i >= total) return;
  int c = i % C;
  float v = (x[i] - stats[c]) * stats[C + c] * g[c] + bb[c];
  v = fmaxf(v, 0.f);
  float r = ADD ? base[i] + v : v;
  outf[i] = r;
  u16 h = f2bf(r);
  ph[i] = h;
  pl[i] = f2bf(r - bf2f(h));
}

__global__ void k_pool(const u16* __restrict__ fh, const u16* __restrict__ fl,
                       const int* __restrict__ idxp, u16* __restrict__ oh,
                       u16* __restrict__ ol, int Nin, int pn, int C) {
  int b = blockIdx.y, p = blockIdx.x, c = threadIdx.x;
  const int* ir = idxp + ((size_t)b * pn + p) * 4;
  const u16* fhb = fh + (size_t)b * Nin * C;
  const u16* flb = fl + (size_t)b * Nin * C;
  float acc = -FLT_MAX;
#pragma unroll
  for (int k = 0; k < 4; ++k) {
    size_t o = (size_t)ir[k] * C + c;
    acc = fmaxf(acc, bf2f(fhb[o]) + bf2f(flb[o]));
  }
  u16 h = f2bf(acc);
  oh[((size_t)b * pn + p) * C + c] = h;
  ol[((size_t)b * pn + p) * C + c] = f2bf(acc - bf2f(h));
}

__global__ void k_maxn(const u16* __restrict__ fh, const u16* __restrict__ fl,
                       float* __restrict__ out, int N, int C) {
  int b = blockIdx.y;
  int c = blockIdx.x * 256 + threadIdx.x;
  if (c >= C) return;
  float acc = -FLT_MAX;
  for (int n = 0; n < N; ++n) {
    size_t o = ((size_t)b * N + n) * C + c;
    acc = fmaxf(acc, bf2f(fh[o]) + bf2f(fl[o]));
  }
  out[(size_t)b * C + c] = acc;
}

__global__ void k_nearest(const float* __restrict__ v, int Ns, int* __restrict__ out) {
  extern __shared__ float sp[];
  int b = blockIdx.y;
  const float* vsb = v + (size_t)b * VS0;
  for (int i = threadIdx.x; i < Ns * 3; i += 256) sp[i] = vsb[i];
  __syncthreads();
  int t = blockIdx.x * 256 + threadIdx.x;
  float tx = vsb[t * 3], ty = vsb[t * 3 + 1], tz = vsb[t * 3 + 2];
  float bd = FLT_MAX; int bi = 0;
#pragma unroll 4
  for (int s = 0; s < Ns; ++s) {
    float dx = sp[s * 3] - tx, dy = sp[s * 3 + 1] - ty, dz = sp[s * 3 + 2] - tz;
    float dd = dx * dx + dy * dy + dz * dz;
    if (dd < bd) { bd = dd; bi = s; }
  }
  out[(size_t)b * NP0 + t] = bi;
}

__global__ void k_glob1(const float* __restrict__ fglob, const float* __restrict__ onehot,
                        const float* __restrict__ h1w, const float* __restrict__ h1b,
                        float* __restrict__ out) {
  int b = blockIdx.x, j = threadIdx.x;
  float s = h1b[j];
  for (int i = 0; i < 512; ++i) s = fmaf(fglob[b * 512 + i], h1w[(size_t)(1280 + i) * 512 + j], s);
  for (int i = 0; i < 16; ++i) s = fmaf(onehot[b * 16 + i], h1w[(size_t)(1792 + i) * 512 + j], s);
  out[b * 512 + j] = s;
}

__global__ void k_logsoftmax(float* __restrict__ x, int rows, int C) {
  int r = blockIdx.x * 4 + (threadIdx.x >> 6);
  int lane = threadIdx.x & 63;
  if (r >= rows) return;
  float* xr = x + (size_t)r * C;
  float v = (lane < C) ? xr[lane] : -FLT_MAX;
  float mx = v;
  for (int o = 32; o; o >>= 1) mx = fmaxf(mx, __shfl_xor(mx, o));
  float e = (lane < C) ? __expf(v - mx) : 0.f;
  float s = e;
  for (int o = 32; o; o >>= 1) s += __shfl_xor(s, o);
  float lse = mx + logf(s);
  if (lane < C) xr[lane] = v - lse;
}

// ===========================================================================
// host
// ===========================================================================
struct Ws {
  float *v0, *v4, *fglob, *glob1, *mx, *inv, *csump, *stats, *bpart, *xcur, *pre, *fout, *xrp, *spart;
  int *idx0, *idxp0, *idx1, *idxp1, *idx2, *ni1, *ni2;
  u16 *wh, *wl;
  u16 *fm0h, *fm0l, *fm1h, *fm1l, *fm2h, *fm2l, *fm3h, *fm3l, *fm4h, *fm4l;
  u16 *fmp1h, *fmp1l, *fmp2h, *fmp2l, *qh, *ql, *vmh, *vml, *xsh, *xsl;
  u16 *x1h, *x2b, *xcat;
};

static void run_sa(hipStream_t st, Ws& ws, int N, int C, int Q,
                   const u16* qkvh, const u16* qkvl, const u16* twh, const u16* twl,
                   const float* vb, const float* tb, const float* g, const float* be,
                   u16* xh, u16* xl) {
  const long sx = (long)N * C;
  mmp<64, 0, 0, 4, false, false>(st, xh, xl, qkvh, qkvl, vb, ws.qh, ws.ql,
                                 N, Q + C, C, sx, 0, (long)N * Q, BB, 1,
                                 nullptr, 0, ws.vmh, ws.vml, Q, sx);
  if (Q == 32) {        // N=2048: stats NS=4, xr NSPLIT=2
    float* Sp = ws.spart + (size_t)4 * BB * N;
    k_sa_stats<32, 4><<<dim3(N / 64, BB, 4), 256, 0, st>>>(ws.qh, ws.ql, N,
        nullptr, nullptr, ws.spart, Sp);
    k_smerge<4><<<(BB * N + 255) / 256, 256, 0, st>>>(ws.spart, Sp, ws.mx, ws.inv, BB * N);
    dim3 gx(N / 64, C / 128, BB * 2);
    k_sa_xr<32, 2><<<gx, 256, 0, st>>>(ws.qh, ws.ql, ws.vmh, ws.vml, ws.mx, ws.inv,
                                       nullptr, nullptr, nullptr, ws.xrp, ws.csump, N, C);
    k_xsub2<2><<<((size_t)BB * N * C + 255) / 256, 256, 0, st>>>(
        ws.xrp, ws.csump, ws.xcur, ws.xsh, ws.xsl, N, C);
  } else if (Q == 64) { // N=512: stats NS=4, xr NSPLIT=4
    float* Sp = ws.spart + (size_t)4 * BB * N;
    k_sa_stats<64, 4><<<dim3(N / 64, BB, 4), 256, 0, st>>>(ws.qh, ws.ql, N,
        nullptr, nullptr, ws.spart, Sp);
    k_smerge<4><<<(BB * N + 255) / 256, 256, 0, st>>>(ws.spart, Sp, ws.mx, ws.inv, BB * N);
    dim3 gx(N / 64, C / 128, BB * 4);
    k_sa_xr<64, 4><<<gx, 256, 0, st>>>(ws.qh, ws.ql, ws.vmh, ws.vml, ws.mx, ws.inv,
                                       nullptr, nullptr, nullptr, ws.xrp, ws.csump, N, C);
    k_xsub2<4><<<((size_t)BB * N * C + 255) / 256, 256, 0, st>>>(
        ws.xrp, ws.csump, ws.xcur, ws.xsh, ws.xsl, N, C);
  } else {              // N=128: no split
    k_sa_stats<128, 1><<<dim3(N / 64, BB, 1), 256, 0, st>>>(ws.qh, ws.ql, N,
        ws.mx, ws.inv, nullptr, nullptr);
    dim3 gx(N / 64, C / 128, BB);
    k_sa_xr<128, 1><<<gx, 256, 0, st>>>(ws.qh, ws.ql, ws.vmh, ws.vml, ws.mx, ws.inv,
                                        ws.xcur, ws.xsh, ws.xsl, nullptr, nullptr, N, C);
  }
  mmp<64, 0, 1, 0, false, false>(st, ws.xsh, ws.xsl, twh, twl, tb, ws.pre, nullptr,
                                 N, C, C, sx, 0, sx, BB, 1);
  k_bn_part<<<256, 256, 0, st>>>(ws.pre, BB * N, C, ws.bpart);
  k_bn_fin<<<(C + 31) / 32, 256, 0, st>>>(ws.bpart, BB * N, C, ws.stats);
  k_bn_apply<true><<<(BB * N * C + 255) / 256, 256, 0, st>>>(ws.pre, ws.stats, g, be,
                                                             ws.xcur, ws.xcur, xh, xl, BB * N * C, C);
}

static void run_conv(hipStream_t st, Ws& ws, const u16* finh, const u16* finl, int Cin,
                     const u16* cwh, const u16* cwl, const float* bias, const float* dirs,
                     const int* idx, int N, int C,
                     const float* bng, const float* bnb, bool doBN, u16* fmh, u16* fml) {
  if (N == NP0)
    mmp<128, 0, 1, 0, false, false>(st, finh, finl, cwh, cwl, bias, ws.fout, nullptr,
                                    N, 2 * C, Cin, (long)N * Cin, 0, (long)N * 2 * C, BB, 1);
  else
    mmp<64, 0, 1, 0, false, false>(st, finh, finl, cwh, cwl, bias, ws.fout, nullptr,
                                   N, 2 * C, Cin, (long)N * Cin, 0, (long)N * 2 * C, BB, 1);
  if (C == 128)
    k_conv_layer<4><<<dim3(N, BB), 512, 0, st>>>(ws.v0, idx, dirs, ws.fout, ws.xcur, N, C);
  else if (C == 256)
    k_conv_layer<2><<<dim3(N, BB), 512, 0, st>>>(ws.v0, idx, dirs, ws.fout, ws.xcur, N, C);
  else
    k_conv_layer<2><<<dim3(N, BB), 1024, 0, st>>>(ws.v0, idx, dirs, ws.fout, ws.xcur, N, C);
  if (doBN) {
    k_bn_part<<<256, 256, 0, st>>>(ws.xcur, BB * N, C, ws.bpart);
    k_bn_fin<<<(C + 31) / 32, 256, 0, st>>>(ws.bpart, BB * N, C, ws.stats);
    k_bn_apply<false><<<(BB * N * C + 255) / 256, 256, 0, st>>>(
        ws.xcur, ws.stats, bng, bnb, nullptr, ws.xcur, fmh, fml, BB * N * C, C);
  } else {
    k_split4<false, true><<<(BB * N * C / 4 + 255) / 256, 256, 0, st>>>(
        ws.xcur, fmh, fml, BB * N * C / 4);
  }
}

extern "C" void kernel_launch(void* const* d_in, const int* in_sizes, int n_in,
                              void* d_out, int out_size, void* d_ws, size_t ws_size,
                              hipStream_t stream) {
  auto in = [&](int i) { return (const float*)d_in[i]; };
  char* p = (char*)d_ws;
  Ws ws;
  ws.v0 = (float*)(p + O_V0);
  ws.v4 = (float*)(p + O_V4);
  ws.idx0 = (int*)(p + O_IDX0); ws.idxp0 = (int*)(p + O_IDXP0);
  ws.idx1 = (int*)(p + O_IDX1); ws.idxp1 = (int*)(p + O_IDXP1);
  ws.idx2 = (int*)(p + O_IDX2);
  ws.ni1 = (int*)(p + O_NI1); ws.ni2 = (int*)(p + O_NI2);
  ws.fglob = (float*)(p + O_FGLOB); ws.glob1 = (float*)(p + O_GLOB1);
  ws.mx = (float*)(p + O_COLS); ws.inv = (float*)(p + O_CPART);
  ws.csump = (float*)(p + O_CPART + 65536);
  ws.stats = (float*)(p + O_STATS); ws.bpart = (float*)(p + O_BPART);
  ws.xcur = (float*)(p + O_XCUR);
  ws.pre = (float*)(p + O_AREA);
  ws.fout = (float*)(p + O_AREA);
  ws.xrp = (float*)(p + O_AREA);
  ws.spart = (float*)(p + O_AREA);
  ws.xcat = (u16*)(p + O_AREA);
  char* pl = p + O_PL;
  ws.wh = (u16*)(pl + PL_WH); ws.wl = (u16*)(pl + PL_WL);
  ws.fm0h = (u16*)(pl + PL_FM0H); ws.fm0l = (u16*)(pl + PL_FM0L);
  ws.fm1h = (u16*)(pl + PL_FM1H); ws.fm1l = (u16*)(pl + PL_FM1L);
  ws.fm2h = (u16*)(pl + PL_FM2H); ws.fm2l = (u16*)(pl + PL_FM2L);
  ws.fm3h = (u16*)(pl + PL_FM3H); ws.fm3l = (u16*)(pl + PL_FM3L);
  ws.fm4h = (u16*)(pl + PL_FM4H); ws.fm4l = (u16*)(pl + PL_FM4L);
  ws.fmp1h = (u16*)(pl + PL_FMP1H); ws.fmp1l = (u16*)(pl + PL_FMP1L);
  ws.fmp2h = (u16*)(pl + PL_FMP2H); ws.fmp2l = (u16*)(pl + PL_FMP2L);
  ws.qh = (u16*)(pl + PL_QH); ws.ql = (u16*)(pl + PL_QL);
  ws.vmh = (u16*)(pl + PL_VMH); ws.vml = (u16*)(pl + PL_VML);
  ws.xsh = (u16*)(pl + PL_XSH); ws.xsl = (u16*)(pl + PL_XSL);
  ws.x1h = (u16*)(pl + PL_X1H);
  ws.x2b = (u16*)(p + O_XCUR);
  float* out = (float*)d_out;

  // ---- one-time weight plane split (pre-transposed to [N,K]) ----
  SplitJobs jobs;
  size_t wq[22];
  size_t off = 0;
  int ji = 0;
  auto addjob = [&](const float* s, int K, int N, int trans) {
    int n = K * N;
    jobs.j[ji] = {s, ws.wh + off, ws.wl + off, n, K, N, trans};
    wq[ji] = off; off += (size_t)n; ++ji;
  };
  addjob(in(5), 128, 32, 0);  addjob(in(6), 128, 128, 0);  addjob(in(8), 128, 128, 0);
  addjob(in(17), 128, 32, 0); addjob(in(18), 128, 128, 0); addjob(in(20), 128, 128, 0);
  addjob(in(29), 256, 64, 0); addjob(in(30), 256, 256, 0); addjob(in(32), 256, 256, 0);
  addjob(in(41), 256, 64, 0); addjob(in(42), 256, 256, 0); addjob(in(44), 256, 256, 0);
  addjob(in(51), 512, 128, 0); addjob(in(52), 512, 512, 0); addjob(in(54), 512, 512, 0);
  addjob(in(12), 128, 256, 1);   // conv1
  addjob(in(24), 128, 512, 1);   // conv2
  addjob(in(36), 256, 512, 1);   // conv3
  addjob(in(48), 256, 1024, 1);  // conv4
  addjob(in(58), 1280, 512, 1);  // h1 combined [512][1280]
  addjob(in(60), 512, 512, 1);   // h2
  addjob(in(62), 512, 50, 1);    // h3
  k_splitjobs<<<dim3(32, 22), 256, 0, stream>>>(jobs);
  auto W = [&](int i) { return ws.wh + wq[i]; };
  auto Wl = [&](int i) { return ws.wl + wq[i]; };

  // ---- geometry ----
  k_transpose<<<(BB * NP0 * 3 + 255) / 256, 256, 0, stream>>>(in(0), ws.v0, ws.v4);
  k_knn_radix<NP0, KNB_><<<dim3(NP0 / 4, BB), 256, 0, stream>>>(
      (const float4*)ws.v4, NP0, ws.idx0);

  // ---- conv0 + bn0 ----
  k_conv_surface<4><<<dim3(NP0, BB), 512, 0, stream>>>(ws.v0, ws.idx0, in(2), ws.xcur, NP0, 128);
  k_bn_part<<<256, 256, 0, stream>>>(ws.xcur, BB * NP0, 128, ws.bpart);
  k_bn_fin<<<4, 256, 0, stream>>>(ws.bpart, BB * NP0, 128, ws.stats);
  k_bn_apply<false><<<(BB * NP0 * 128 + 255) / 256, 256, 0, stream>>>(
      ws.xcur, ws.stats, in(3), in(4), nullptr, ws.xcur, ws.fm0h, ws.fm0l, BB * NP0 * 128, 128);

  // ---- sa0, conv1+bn1, sa1 ----
  run_sa(stream, ws, NP0, 128, 32, W(0), Wl(0), W(2), Wl(2),
         in(7), in(9), in(10), in(11), ws.fm0h, ws.fm0l);
  run_conv(stream, ws, ws.fm0h, ws.fm0l, 128, W(15), Wl(15), in(13), in(14), ws.idx0,
           NP0, 128, in(15), in(16), true, ws.fm1h, ws.fm1l);
  run_sa(stream, ws, NP0, 128, 32, W(3), Wl(3), W(5), Wl(5),
         in(19), in(21), in(22), in(23), ws.fm1h, ws.fm1l);

  // ---- pool1, knn1 ----
  k_knn2<NP0, 4><<<dim3(NP1 / 4, BB), 256, 0, stream>>>((const float4*)ws.v4, NP1, ws.idxp0);
  k_pool<<<dim3(NP1, BB), 128, 0, stream>>>(ws.fm1h, ws.fm1l, ws.idxp0,
                                            ws.fmp1h, ws.fmp1l, NP0, NP1, 128);
  k_knn_radix<NP1, KNB_><<<dim3(NP1 / 4, BB), 256, 0, stream>>>(
      (const float4*)ws.v4, NP1, ws.idx1);

  // ---- conv2+bn2, sa2, conv3+bn3, sa3 ----
  run_conv(stream, ws, ws.fmp1h, ws.fmp1l, 128, W(16), Wl(16), in(25), in(26), ws.idx1,
           NP1, 256, in(27), in(28), true, ws.fm2h, ws.fm2l);
  run_sa(stream, ws, NP1, 256, 64, W(6), Wl(6), W(8), Wl(8),
         in(31), in(33), in(34), in(35), ws.fm2h, ws.fm2l);
  run_conv(stream, ws, ws.fm2h, ws.fm2l, 256, W(17), Wl(17), in(37), in(38), ws.idx1,
           NP1, 256, in(39), in(40), true, ws.fm3h, ws.fm3l);
  run_sa(stream, ws, NP1, 256, 64, W(9), Wl(9), W(11), Wl(11),
         in(43), in(45), in(46), in(47), ws.fm3h, ws.fm3l);

  // ---- pool2, knn2, conv4 (no bn), sa4 ----
  k_knn2<NP1, 4><<<dim3(NP2 / 4, BB), 256, 0, stream>>>((const float4*)ws.v4, NP2, ws.idxp1);
  k_pool<<<dim3(NP2, BB), 256, 0, stream>>>(ws.fm3h, ws.fm3l, ws.idxp1,
                                            ws.fmp2h, ws.fmp2l, NP1, NP2, 256);
  k_knn_radix<NP2, KNB_><<<dim3(NP2 / 4, BB), 256, 0, stream>>>(
      (const float4*)ws.v4, NP2, ws.idx2);
  run_conv(stream, ws, ws.fmp2h, ws.fmp2l, 256, W(18), Wl(18), in(49), in(50), ws.idx2,
           NP2, 512, nullptr, nullptr, false, ws.fm4h, ws.fm4l);
  run_sa(stream, ws, NP2, 512, 128, W(12), Wl(12), W(14), Wl(14),
         in(53), in(55), in(56), in(57), ws.fm4h, ws.fm4l);

  // ---- global max, nearest, head ----
  k_maxn<<<dim3(2, BB), 256, 0, stream>>>(ws.fm4h, ws.fm4l, ws.fglob, NP2, 512);
  k_nearest<<<dim3(NP0 / 256, BB), 256, NP1 * 3 * 4, stream>>>(ws.v0, NP1, ws.ni1);
  k_nearest<<<dim3(NP0 / 256, BB), 256, NP2 * 3 * 4, stream>>>(ws.v0, NP2, ws.ni2);
  k_glob1<<<BB, 512, 0, stream>>>(ws.fglob, in(1), in(58), in(59), ws.glob1);

  for (int hf = 0; hf < 2; ++hf) {
    const int b0 = hf * 4;
    k_xcat<<<(4 * NP0 * 160 + 255) / 256, 256, 0, stream>>>(
        ws.fm0h, ws.fm1h, ws.fm2h, ws.fm3h, ws.fm4h, ws.ni1, ws.ni2, ws.xcat, b0);
    mmp<128, 2, 2, 3, false, false, false>(stream, ws.xcat, nullptr, W(19), nullptr,
        ws.glob1 + b0 * 512, ws.x1h, nullptr,
        NP0, 512, 1280, (long)NP0 * 1280, 0, (long)NP0 * 512, 4, 1);
    mmp<128, 2, 1, 3, false, false, false>(stream, ws.x1h, nullptr, W(20), nullptr, in(61),
        ws.x2b, nullptr, NP0, 512, 512, (long)NP0 * 512, 0, (long)NP0 * 512, 4, 1);
    mmp<64, 2, 1, 0, false, false, false>(stream, ws.x2b, nullptr, W(21), nullptr, in(63),
        out + (size_t)b0 * NP0 * 50, nullptr, NP0, 50, 512,
        (long)NP0 * 512, 0, (long)NP0 * 50, 4, 1);
  }

  k_logsoftmax<<<(BB * NP0) / 4, 256, 0, stream>>>(out, BB * NP0, 50);
}

// Round 18
// 1101.231 us; speedup vs baseline: 1.1156x; 1.1156x over previous
//
#include <hip/hip_runtime.h>
#include <cfloat>

// ---------------------------------------------------------------------------
// GCN3D forward. Split-plane bf16 MFMA GEMMs (Dekker, f32-grade accuracy).
// Round-18: revert round-17's KG split (raised instr count, 69->92us). Instead
// vectorize conv kernels: each thread owns 4 consecutive channels (float4
// gather loads, VMEM instr /4, su/sidx broadcast amortized). Bit-identical
// math. Block=256 covers {8,4,2} points for C={128,256,512}.
// B=8, N=2048->512->128, K_NB=50. Workspace ~98.0 MB.
// ---------------------------------------------------------------------------

#define BB   8
#define NP0  2048
#define NP1  512
#define NP2  128
#define KNB_ 50
#define VS0  (NP0 * 3)

typedef __attribute__((ext_vector_type(8))) short short8_t;
typedef __attribute__((ext_vector_type(4))) short short4_t;
typedef __attribute__((ext_vector_type(4))) float f32x4_t;
typedef unsigned short u16;

// ---------------- workspace layout (byte offsets) ----------------
static constexpr size_t O_V0    = 0;
static constexpr size_t O_IDX0  = 196608;
static constexpr size_t O_IDXP0 = 3473408;
static constexpr size_t O_IDX1  = 3538944;
static constexpr size_t O_IDXP1 = 4358144;
static constexpr size_t O_IDX2  = 4374528;
static constexpr size_t O_NI1   = 4579328;
static constexpr size_t O_NI2   = 4644864;
static constexpr size_t O_FGLOB = 4710400;
static constexpr size_t O_GLOB1 = 4726784;
static constexpr size_t O_COLS  = 4743168;   // mx vectors (64KB)
static constexpr size_t O_CPART = 4808704;   // inv(64KB) + csump(128KB) + v4(256KB)
static constexpr size_t O_V4    = O_CPART + 196608;
static constexpr size_t O_STATS = 5332992;
static constexpr size_t O_XCUR  = 5599232;   // 8,388,608 f32 activation scratch
static constexpr size_t O_PL    = 18182144;  // 58,855,424 plane pools
static constexpr size_t O_AREA  = 77037568;  // spart/xrp/fout/pre/xcat (phase-disjoint)
static constexpr size_t O_BPART = O_AREA + 12582912;  // 1MB bn partials

static constexpr size_t PL_WH    = 0;
static constexpr size_t PL_WL    = 4786176;
static constexpr size_t PL_FM0H  = 9572352;
static constexpr size_t PL_FM0L  = 13766656;
static constexpr size_t PL_FM1H  = 17960960;
static constexpr size_t PL_FM1L  = 22155264;
static constexpr size_t PL_FM2H  = 26349568;
static constexpr size_t PL_FM2L  = 28446720;
static constexpr size_t PL_FM3H  = 30543872;
static constexpr size_t PL_FM3L  = 32641024;
static constexpr size_t PL_FM4H  = 34738176;
static constexpr size_t PL_FM4L  = 35786752;
static constexpr size_t PL_FMP1H = 36835328;
static constexpr size_t PL_FMP1L = 37883904;
static constexpr size_t PL_FMP2H = 38932480;
static constexpr size_t PL_FMP2L = 39456768;
static constexpr size_t PL_QH    = 39981056;
static constexpr size_t PL_QL    = 41029632;
static constexpr size_t PL_VMH   = 42078208;
static constexpr size_t PL_VML   = 46272512;
static constexpr size_t PL_XSH   = 50466816;
static constexpr size_t PL_XSL   = 54661120;
static constexpr size_t PL_X1H = PL_VMH;   // head alias (vm planes dead at head)

__device__ __forceinline__ float bf2f(u16 h) {
  union { unsigned u; float f; } c; c.u = ((unsigned)h) << 16; return c.f;
}
__device__ __forceinline__ u16 f2bf(float f) {
  union { float f; unsigned u; } c; c.f = f;
  return (u16)((c.u + 0x7fffu + ((c.u >> 16) & 1u)) >> 16);
}

// ===========================================================================
// Plane GEMM. BSPLIT=false: B hi-plane only. AMODE 2: plain bf16 A.
// OUTM 4: merged q+vm epilogue.
// ===========================================================================
template <int TM, int AMODE, int BIASM, int OUTM, bool ACC, bool GIDX, bool BSPLIT = true>
__global__ __launch_bounds__(256) void k_mmp(
    const void* __restrict__ A1, const void* __restrict__ A2,
    const u16* __restrict__ Bh0, const u16* __restrict__ Bl0,
    const float* __restrict__ bias, void* __restrict__ C1, void* __restrict__ C2,
    int M, int N, int K, long sA, long sB, long sC, int ksplit,
    const int* __restrict__ gidx, long sG,
    void* __restrict__ C3, void* __restrict__ C4, int QQ, long sCv) {
  constexpr int RT = TM / 32;
  constexpr int CT = TM / 32;
  __shared__ u16 Ah[TM][40], Bh[TM][40];
  __shared__ u16 Bl[BSPLIT ? TM : 1][40];
  __shared__ u16 Al[(AMODE == 2) ? 1 : TM][40];
  const int z = blockIdx.z;
  const int zb = z / ksplit, ks = z - zb * ksplit;
  const int kchunk = K / ksplit;
  const int kl0 = ks * kchunk, kl1 = kl0 + kchunk;
  const int m0 = blockIdx.x * TM, n0 = blockIdx.y * TM;
  const int t = threadIdx.x;
  const int lane = t & 63, w = t >> 6;
  const int wr = (w >> 1) * (TM / 2), wc = (w & 1) * (TM / 2);
  const int frow = lane & 15, koff = (lane >> 4) * 8;
  f32x4_t acc[RT][CT];
#pragma unroll
  for (int i = 0; i < RT; ++i)
#pragma unroll
    for (int j = 0; j < CT; ++j) acc[i][j] = (f32x4_t){0.f, 0.f, 0.f, 0.f};

  const u16* Ahg = (const u16*)A1 + (size_t)zb * sA;
  const u16* Alg = (const u16*)A2 + (size_t)zb * sA;
  const u16* Bhg = Bh0 + (size_t)zb * sB;
  const u16* Blg = Bl0 + (size_t)zb * sB;

  int ar, ac, arow = 0;
  if constexpr (TM == 128) { ar = t >> 1; ac = (t & 1) * 16; }
  else                     { ar = t >> 2; ac = (t & 3) * 8; }
  arow = m0 + ar;
  if constexpr (GIDX) arow = (gidx + (size_t)zb * sG)[arow];
  const int bn = ar, bc = ac;
  const bool bok = (n0 + bn) < N;
  const short8_t z8 = {0, 0, 0, 0, 0, 0, 0, 0};

  for (int k0 = kl0; k0 < kl1; k0 += 32) {
    __syncthreads();
    {
      const u16* s1 = Ahg + (size_t)arow * K + k0 + ac;
      if constexpr (TM == 128) {
        *(short8_t*)&Ah[ar][ac] = *(const short8_t*)s1;
        *(short8_t*)&Ah[ar][ac + 8] = *(const short8_t*)(s1 + 8);
        if constexpr (AMODE == 0) {
          const u16* s2 = Alg + (size_t)arow * K + k0 + ac;
          *(short8_t*)&Al[ar][ac] = *(const short8_t*)s2;
          *(short8_t*)&Al[ar][ac + 8] = *(const short8_t*)(s2 + 8);
        }
      } else {
        *(short8_t*)&Ah[ar][ac] = *(const short8_t*)s1;
        if constexpr (AMODE == 0)
          *(short8_t*)&Al[ar][ac] = *(const short8_t*)(Alg + (size_t)arow * K + k0 + ac);
      }
    }
    {
      const u16* s1 = Bhg + (size_t)(n0 + bn) * K + k0 + bc;
      const u16* s2 = Blg + (size_t)(n0 + bn) * K + k0 + bc;
      if constexpr (TM == 128) {
        *(short8_t*)&Bh[bn][bc] = bok ? *(const short8_t*)s1 : z8;
        *(short8_t*)&Bh[bn][bc + 8] = bok ? *(const short8_t*)(s1 + 8) : z8;
        if constexpr (BSPLIT) {
          *(short8_t*)&Bl[bn][bc] = bok ? *(const short8_t*)s2 : z8;
          *(short8_t*)&Bl[bn][bc + 8] = bok ? *(const short8_t*)(s2 + 8) : z8;
        }
      } else {
        *(short8_t*)&Bh[bn][bc] = bok ? *(const short8_t*)s1 : z8;
        if constexpr (BSPLIT)
          *(short8_t*)&Bl[bn][bc] = bok ? *(const short8_t*)s2 : z8;
      }
    }
    __syncthreads();
    short8_t ah[RT], al[RT], bh[CT], bl[CT];
#pragma unroll
    for (int i = 0; i < RT; ++i) {
      const int r = wr + i * 16 + frow;
      ah[i] = *(const short8_t*)&Ah[r][koff];
      if constexpr (AMODE != 2) al[i] = *(const short8_t*)&Al[r][koff];
    }
#pragma unroll
    for (int i = 0; i < CT; ++i) {
      const int r = wc + i * 16 + frow;
      bh[i] = *(const short8_t*)&Bh[r][koff];
      if constexpr (BSPLIT) bl[i] = *(const short8_t*)&Bl[r][koff];
    }
#pragma unroll
    for (int i = 0; i < RT; ++i)
#pragma unroll
      for (int j = 0; j < CT; ++j) {
        acc[i][j] = __builtin_amdgcn_mfma_f32_16x16x32_bf16(ah[i], bh[j], acc[i][j], 0, 0, 0);
        if constexpr (BSPLIT)
          acc[i][j] = __builtin_amdgcn_mfma_f32_16x16x32_bf16(ah[i], bl[j], acc[i][j], 0, 0, 0);
        if constexpr (AMODE != 2)
          acc[i][j] = __builtin_amdgcn_mfma_f32_16x16x32_bf16(al[i], bh[j], acc[i][j], 0, 0, 0);
      }
  }

  const int crow = (lane >> 4) * 4;
#pragma unroll
  for (int i = 0; i < RT; ++i) {
#pragma unroll
    for (int j = 0; j < CT; ++j) {
      const int gc = n0 + wc + j * 16 + frow;
      if (gc >= N) continue;
      float bv = 0.f;
      if constexpr (BIASM == 1) bv = bias[gc];
      if constexpr (BIASM == 2) bv = bias[(size_t)zb * N + gc];
      const int gr0 = m0 + wr + i * 16 + crow;
      if constexpr (OUTM == 0) {
        float* Cp = (float*)C1 + (size_t)z * sC;
#pragma unroll
        for (int q = 0; q < 4; ++q) {
          float vv = acc[i][j][q] + bv;
          if (ACC) vv += Cp[(size_t)(gr0 + q) * N + gc];
          Cp[(size_t)(gr0 + q) * N + gc] = vv;
        }
      } else if constexpr (OUTM == 1) {
        u16* Ph = (u16*)C1 + (size_t)z * sC;
        u16* Pl = (u16*)C2 + (size_t)z * sC;
#pragma unroll
        for (int q = 0; q < 4; ++q) {
          float vv = acc[i][j][q] + bv;
          u16 h = f2bf(vv);
          Ph[(size_t)(gr0 + q) * N + gc] = h;
          Pl[(size_t)(gr0 + q) * N + gc] = f2bf(vv - bf2f(h));
        }
      } else if constexpr (OUTM == 2) {
        u16* Ph = (u16*)C1 + (size_t)z * sC;
        u16* Pl = (u16*)C2 + (size_t)z * sC;
        short4_t h4, l4;
#pragma unroll
        for (int q = 0; q < 4; ++q) {
          float vv = acc[i][j][q] + bv;
          u16 h = f2bf(vv);
          h4[q] = (short)h;
          l4[q] = (short)f2bf(vv - bf2f(h));
        }
        *(short4_t*)(Ph + (size_t)gc * M + gr0) = h4;
        *(short4_t*)(Pl + (size_t)gc * M + gr0) = l4;
      } else if constexpr (OUTM == 4) {
        if (gc < QQ) {
          u16* Ph = (u16*)C1 + (size_t)zb * sC;
          u16* Pl = (u16*)C2 + (size_t)zb * sC;
#pragma unroll
          for (int q = 0; q < 4; ++q) {
            float vv = acc[i][j][q];
            u16 h = f2bf(vv);
            Ph[(size_t)(gr0 + q) * QQ + gc] = h;
            Pl[(size_t)(gr0 + q) * QQ + gc] = f2bf(vv - bf2f(h));
          }
        } else {
          const int cv = gc - QQ;
          const float bv2 = bias[cv];
          u16* Th = (u16*)C3 + (size_t)zb * sCv;
          u16* Tl = (u16*)C4 + (size_t)zb * sCv;
          short4_t h4, l4;
#pragma unroll
          for (int q = 0; q < 4; ++q) {
            float vv = acc[i][j][q] + bv2;
            u16 h = f2bf(vv);
            h4[q] = (short)h;
            l4[q] = (short)f2bf(vv - bf2f(h));
          }
          *(short4_t*)(Th + (size_t)cv * M + gr0) = h4;
          *(short4_t*)(Tl + (size_t)cv * M + gr0) = l4;
        }
      } else {  // OUTM 3: relu -> plain bf16
        u16* Cb = (u16*)C1 + (size_t)z * sC;
#pragma unroll
        for (int q = 0; q < 4; ++q) {
          float vv = fmaxf(acc[i][j][q] + bv, 0.f);
          Cb[(size_t)(gr0 + q) * N + gc] = f2bf(vv);
        }
      }
    }
  }
}

template <int TM, int AMODE, int BIASM, int OUTM, bool ACC, bool GIDX, bool BSPLIT = true>
static void mmp(hipStream_t st, const void* A1, const void* A2,
                const u16* Bh, const u16* Bl, const float* bias,
                void* C1, void* C2, int M, int N, int K,
                long sA, long sB, long sC, int Z, int ksplit,
                const int* gidx = nullptr, long sG = 0,
                void* C3 = nullptr, void* C4 = nullptr, int QQ = 0, long sCv = 0) {
  dim3 grid(M / TM, (N + TM - 1) / TM, Z * ksplit);
  k_mmp<TM, AMODE, BIASM, OUTM, ACC, GIDX, BSPLIT><<<grid, 256, 0, st>>>(
      A1, A2, Bh, Bl, bias, C1, C2, M, N, K, sA, sB, sC, ksplit, gidx, sG,
      C3, C4, QQ, sCv);
}

// ===========================================================================
// Fused attention. stats NSPLIT partials + merge; xr NSPLIT.
// ===========================================================================
template <int QD, int NS>
__global__ __launch_bounds__(256) void k_sa_stats(
    const u16* __restrict__ qh, const u16* __restrict__ ql, int N,
    float* __restrict__ mx, float* __restrict__ inv,
    float* __restrict__ Mp, float* __restrict__ Sp) {
  __shared__ float mr[2][64], sr[2][64];
  const int b = blockIdx.y;
  const int m0 = blockIdx.x * 64;
  const int sidx = blockIdx.z;
  const int t = threadIdx.x, lane = t & 63, w = t >> 6;
  const int wm = (w >> 1) * 32, wn = (w & 1) * 64;
  const int frow = lane & 15, kq = (lane >> 4) * 8;
  const u16* qhb = qh + (size_t)b * N * QD;
  const u16* qlb = ql + (size_t)b * N * QD;
  constexpr int KS = QD / 32;
  short8_t ahq[KS][2], alq[KS][2];
#pragma unroll
  for (int ks = 0; ks < KS; ++ks)
#pragma unroll
    for (int i = 0; i < 2; ++i) {
      const size_t r = (size_t)(m0 + wm + i * 16 + frow) * QD + ks * 32 + kq;
      ahq[ks][i] = *(const short8_t*)(qhb + r);
      alq[ks][i] = *(const short8_t*)(qlb + r);
    }
  float M[2][4], S[2][4];
#pragma unroll
  for (int i = 0; i < 2; ++i)
#pragma unroll
    for (int q = 0; q < 4; ++q) { M[i][q] = -FLT_MAX; S[i][q] = 0.f; }

  const int nlo = sidx * (N / NS), nhi = nlo + N / NS;
  for (int n0 = nlo; n0 < nhi; n0 += 128) {
    f32x4_t acc[2][4];
#pragma unroll
    for (int i = 0; i < 2; ++i)
#pragma unroll
      for (int j = 0; j < 4; ++j) acc[i][j] = (f32x4_t){0.f, 0.f, 0.f, 0.f};
#pragma unroll
    for (int ks = 0; ks < KS; ++ks) {
      short8_t b_h[4], b_l[4];
#pragma unroll
      for (int j = 0; j < 4; ++j) {
        const size_t r = (size_t)(n0 + wn + j * 16 + frow) * QD + ks * 32 + kq;
        b_h[j] = *(const short8_t*)(qhb + r);
        b_l[j] = *(const short8_t*)(qlb + r);
      }
#pragma unroll
      for (int i = 0; i < 2; ++i)
#pragma unroll
        for (int j = 0; j < 4; ++j) {
          acc[i][j] = __builtin_amdgcn_mfma_f32_16x16x32_bf16(ahq[ks][i], b_h[j], acc[i][j], 0, 0, 0);
          acc[i][j] = __builtin_amdgcn_mfma_f32_16x16x32_bf16(ahq[ks][i], b_l[j], acc[i][j], 0, 0, 0);
          acc[i][j] = __builtin_amdgcn_mfma_f32_16x16x32_bf16(alq[ks][i], b_h[j], acc[i][j], 0, 0, 0);
        }
    }
#pragma unroll
    for (int i = 0; i < 2; ++i)
#pragma unroll
      for (int q = 0; q < 4; ++q) {
        float tm = acc[i][0][q];
#pragma unroll
        for (int j = 1; j < 4; ++j) tm = fmaxf(tm, acc[i][j][q]);
#pragma unroll
        for (int off = 1; off < 16; off <<= 1) tm = fmaxf(tm, __shfl_xor(tm, off));
        const float Mn = fmaxf(M[i][q], tm);
        float ps = 0.f;
#pragma unroll
        for (int j = 0; j < 4; ++j) ps += __expf(acc[i][j][q] - Mn);
#pragma unroll
        for (int off = 1; off < 16; off <<= 1) ps += __shfl_xor(ps, off);
        S[i][q] = S[i][q] * __expf(M[i][q] - Mn) + ps;
        M[i][q] = Mn;
      }
  }
  if (frow == 0) {
#pragma unroll
    for (int i = 0; i < 2; ++i)
#pragma unroll
      for (int q = 0; q < 4; ++q) {
        const int ml = wm + i * 16 + (lane >> 4) * 4 + q;
        mr[w & 1][ml] = M[i][q];
        sr[w & 1][ml] = S[i][q];
      }
  }
  __syncthreads();
  if (t < 64) {
    const float M0 = mr[0][t], M1 = mr[1][t];
    const float Mm = fmaxf(M0, M1);
    const float Sm = sr[0][t] * __expf(M0 - Mm) + sr[1][t] * __expf(M1 - Mm);
    if constexpr (NS == 1) {
      mx[(size_t)b * N + m0 + t] = Mm;
      inv[(size_t)b * N + m0 + t] = 1.f / Sm;
    } else {
      const size_t o = ((size_t)sidx * BB + b) * N + m0 + t;
      Mp[o] = Mm;
      Sp[o] = Sm;
    }
  }
}

template <int NS>
__global__ void k_smerge(const float* __restrict__ Mp, const float* __restrict__ Sp,
                         float* __restrict__ mx, float* __restrict__ inv, int total) {
  int i = blockIdx.x * 256 + threadIdx.x;
  if (i >= total) return;
  float M = -FLT_MAX;
#pragma unroll
  for (int s = 0; s < NS; ++s) M = fmaxf(M, Mp[(size_t)s * total + i]);
  float S = 0.f;
#pragma unroll
  for (int s = 0; s < NS; ++s)
    S += Sp[(size_t)s * total + i] * __expf(Mp[(size_t)s * total + i] - M);
  mx[i] = M;
  inv[i] = 1.f / S;
}

template <int QD, int NSPLIT>
__global__ __launch_bounds__(256) void k_sa_xr(
    const u16* __restrict__ qh, const u16* __restrict__ ql,
    const u16* __restrict__ vmh, const u16* __restrict__ vml,
    const float* __restrict__ mx, const float* __restrict__ inv,
    const float* __restrict__ xcur, u16* __restrict__ xsh, u16* __restrict__ xsl,
    float* __restrict__ xrp, float* __restrict__ csump,
    int N, int C) {
  __shared__ __align__(16) u16 Ph[64][132];
  __shared__ __align__(16) u16 Vh[128][68], Vl[128][68];
  const int b = blockIdx.z / NSPLIT, sidx = blockIdx.z % NSPLIT;
  const int m0 = blockIdx.x * 64, c0 = blockIdx.y * 128;
  const int t = threadIdx.x, lane = t & 63, w = t >> 6;
  const int wm = (w >> 1) * 32, wn = (w & 1) * 64;
  const int frow = lane & 15, kq = (lane >> 4) * 8;
  const u16* qhb = qh + (size_t)b * N * QD;
  const u16* qlb = ql + (size_t)b * N * QD;
  const u16* vhb = vmh + (size_t)b * (size_t)N * C;
  const u16* vlb = vml + (size_t)b * (size_t)N * C;
  const float* mxb = mx + (size_t)b * N;
  const float* invb = inv + (size_t)b * N;
  constexpr int KS = QD / 32;
  const int vr = t >> 1, vco = (t & 1) * 32;
  short8_t ahq[KS][2], alq[KS][2];
#pragma unroll
  for (int ks = 0; ks < KS; ++ks)
#pragma unroll
    for (int i = 0; i < 2; ++i) {
      const size_t r = (size_t)(m0 + wm + i * 16 + frow) * QD + ks * 32 + kq;
      ahq[ks][i] = *(const short8_t*)(qhb + r);
      alq[ks][i] = *(const short8_t*)(qlb + r);
    }
  f32x4_t xacc[2][4];
  float csum[2][4];
#pragma unroll
  for (int i = 0; i < 2; ++i)
#pragma unroll
    for (int j = 0; j < 4; ++j) { xacc[i][j] = (f32x4_t){0.f, 0.f, 0.f, 0.f}; csum[i][j] = 0.f; }

  const int nlo = sidx * (N / NSPLIT), nhi = nlo + N / NSPLIT;
  for (int n0 = nlo; n0 < nhi; n0 += 128) {
    __syncthreads();
    {
      const u16* s1 = vhb + (size_t)(c0 + vr) * N + n0 + vco;
      const u16* s2 = vlb + (size_t)(c0 + vr) * N + n0 + vco;
#pragma unroll
      for (int u = 0; u < 4; ++u) {
        *(short8_t*)&Vh[vr][vco + u * 8] = *(const short8_t*)(s1 + u * 8);
        *(short8_t*)&Vl[vr][vco + u * 8] = *(const short8_t*)(s2 + u * 8);
      }
    }
    f32x4_t acc[2][4];
#pragma unroll
    for (int i = 0; i < 2; ++i)
#pragma unroll
      for (int j = 0; j < 4; ++j) acc[i][j] = (f32x4_t){0.f, 0.f, 0.f, 0.f};
#pragma unroll
    for (int ks = 0; ks < KS; ++ks) {
      short8_t b_h[4], b_l[4];
#pragma unroll
      for (int j = 0; j < 4; ++j) {
        const size_t r = (size_t)(n0 + wn + j * 16 + frow) * QD + ks * 32 + kq;
        b_h[j] = *(const short8_t*)(qhb + r);
        b_l[j] = *(const short8_t*)(qlb + r);
      }
#pragma unroll
      for (int i = 0; i < 2; ++i)
#pragma unroll
        for (int j = 0; j < 4; ++j) {
          acc[i][j] = __builtin_amdgcn_mfma_f32_16x16x32_bf16(ahq[ks][i], b_h[j], acc[i][j], 0, 0, 0);
          acc[i][j] = __builtin_amdgcn_mfma_f32_16x16x32_bf16(ahq[ks][i], b_l[j], acc[i][j], 0, 0, 0);
          acc[i][j] = __builtin_amdgcn_mfma_f32_16x16x32_bf16(alq[ks][i], b_h[j], acc[i][j], 0, 0, 0);
        }
    }
    float mxj[4], ivj[4];
#pragma unroll
    for (int j = 0; j < 4; ++j) {
      const int n = n0 + wn + j * 16 + frow;
      mxj[j] = mxb[n];
      ivj[j] = invb[n];
    }
    const int mbase = wm + (lane >> 4) * 4;
#pragma unroll
    for (int i = 0; i < 2; ++i)
#pragma unroll
      for (int j = 0; j < 4; ++j)
#pragma unroll
        for (int q = 0; q < 4; ++q) {
          const float pv = __expf(acc[i][j][q] - mxj[j]) * ivj[j];
          csum[i][q] += pv;
          Ph[mbase + i * 16 + q][wn + j * 16 + frow] = f2bf(pv);
        }
    __syncthreads();
#pragma unroll
    for (int ks2 = 0; ks2 < 2; ++ks2) {
      short8_t p_h[2], v_h[4], v_l[4];
#pragma unroll
      for (int i = 0; i < 2; ++i)
        p_h[i] = *(const short8_t*)&Ph[wm + i * 16 + frow][ks2 * 32 + kq];
#pragma unroll
      for (int j = 0; j < 4; ++j) {
        v_h[j] = *(const short8_t*)&Vh[wn + j * 16 + frow][ks2 * 32 + kq];
        v_l[j] = *(const short8_t*)&Vl[wn + j * 16 + frow][ks2 * 32 + kq];
      }
#pragma unroll
      for (int i = 0; i < 2; ++i)
#pragma unroll
        for (int j = 0; j < 4; ++j) {
          xacc[i][j] = __builtin_amdgcn_mfma_f32_16x16x32_bf16(p_h[i], v_h[j], xacc[i][j], 0, 0, 0);
          xacc[i][j] = __builtin_amdgcn_mfma_f32_16x16x32_bf16(p_h[i], v_l[j], xacc[i][j], 0, 0, 0);
        }
    }
    __syncthreads();
    {
      const u16* s1 = vhb + (size_t)(c0 + vr) * N + n0 + 64 + vco;
      const u16* s2 = vlb + (size_t)(c0 + vr) * N + n0 + 64 + vco;
#pragma unroll
      for (int u = 0; u < 4; ++u) {
        *(short8_t*)&Vh[vr][vco + u * 8] = *(const short8_t*)(s1 + u * 8);
        *(short8_t*)&Vl[vr][vco + u * 8] = *(const short8_t*)(s2 + u * 8);
      }
    }
    __syncthreads();
#pragma unroll
    for (int ks2 = 0; ks2 < 2; ++ks2) {
      short8_t p_h[2], v_h[4], v_l[4];
#pragma unroll
      for (int i = 0; i < 2; ++i)
        p_h[i] = *(const short8_t*)&Ph[wm + i * 16 + frow][64 + ks2 * 32 + kq];
#pragma unroll
      for (int j = 0; j < 4; ++j) {
        v_h[j] = *(const short8_t*)&Vh[wn + j * 16 + frow][ks2 * 32 + kq];
        v_l[j] = *(const short8_t*)&Vl[wn + j * 16 + frow][ks2 * 32 + kq];
      }
#pragma unroll
      for (int i = 0; i < 2; ++i)
#pragma unroll
        for (int j = 0; j < 4; ++j) {
          xacc[i][j] = __builtin_amdgcn_mfma_f32_16x16x32_bf16(p_h[i], v_h[j], xacc[i][j], 0, 0, 0);
          xacc[i][j] = __builtin_amdgcn_mfma_f32_16x16x32_bf16(p_h[i], v_l[j], xacc[i][j], 0, 0, 0);
        }
    }
  }
#pragma unroll
  for (int i = 0; i < 2; ++i)
#pragma unroll
    for (int q = 0; q < 4; ++q)
#pragma unroll
      for (int off = 1; off < 16; off <<= 1) csum[i][q] += __shfl_xor(csum[i][q], off);
  __syncthreads();
  float* csb = (float*)&Ph[0][0];
  if (frow == 0) {
#pragma unroll
    for (int i = 0; i < 2; ++i)
#pragma unroll
      for (int q = 0; q < 4; ++q)
        csb[(w & 1) * 64 + wm + i * 16 + (lane >> 4) * 4 + q] = csum[i][q];
  }
  __syncthreads();
  if (t < 64) csb[128 + t] = csb[t] + csb[64 + t];
  __syncthreads();
  if constexpr (NSPLIT > 1) {
    if (t < 64 && blockIdx.y == 0)
      csump[((size_t)sidx * BB + b) * N + m0 + t] = csb[128 + t];
    float* xp = xrp + (size_t)sidx * BB * N * C;
#pragma unroll
    for (int i = 0; i < 2; ++i)
#pragma unroll
      for (int q = 0; q < 4; ++q) {
        const int mloc = wm + i * 16 + (lane >> 4) * 4 + q;
        const size_t rowoff = ((size_t)b * N + m0 + mloc) * C;
#pragma unroll
        for (int j = 0; j < 4; ++j)
          xp[rowoff + c0 + wn + j * 16 + frow] = xacc[i][j][q];
      }
  } else {
#pragma unroll
    for (int i = 0; i < 2; ++i) {
#pragma unroll
      for (int q = 0; q < 4; ++q) {
        const int mloc = wm + i * 16 + (lane >> 4) * 4 + q;
        const float cstot = csb[128 + mloc];
        const size_t rowoff = ((size_t)b * N + m0 + mloc) * C;
#pragma unroll
        for (int j = 0; j < 4; ++j) {
          const int gc = c0 + wn + j * 16 + frow;
          const float val = xcur[rowoff + gc] - xacc[i][j][q] / (1e-9f + cstot);
          const u16 h = f2bf(val);
          xsh[rowoff + gc] = h;
          xsl[rowoff + gc] = f2bf(val - bf2f(h));
        }
      }
    }
  }
}

template <int NS>
__global__ void k_xsub2(const float* __restrict__ xrp, const float* __restrict__ csump,
                        const float* __restrict__ xcur, u16* __restrict__ xsh,
                        u16* __restrict__ xsl, int N, int C) {
  const size_t total = (size_t)BB * N * C;
  size_t i = (size_t)blockIdx.x * 256 + threadIdx.x;
  if (i >= total) return;
  const size_t row = i / C;
  float s = 0.f, cs = 0.f;
#pragma unroll
  for (int k = 0; k < NS; ++k) {
    s += xrp[(size_t)k * total + i];
    cs += csump[(size_t)k * BB * N + row];
  }
  const float val = xcur[i] - s / (1e-9f + cs);
  const u16 h = f2bf(val);
  xsh[i] = h;
  xsl[i] = f2bf(val - bf2f(h));
}

// ===========================================================================
// weight split + activation split + head gather
// ===========================================================================
struct SplitJob { const float* s; u16* dh; u16* dl; int n, K, N, trans; };
struct SplitJobs { SplitJob j[22]; };
__global__ void k_splitjobs(SplitJobs jobs) {
  SplitJob jb = jobs.j[blockIdx.y];
  for (int i = blockIdx.x * 256 + threadIdx.x; i < jb.n; i += gridDim.x * 256) {
    float v;
    if (jb.trans) { int k = i % jb.K, n = i / jb.K; v = jb.s[(size_t)k * jb.N + n]; }
    else v = jb.s[i];
    u16 h = f2bf(v);
    jb.dh[i] = h;
    jb.dl[i] = f2bf(v - bf2f(h));
  }
}

template <bool RELU, bool LO>
__global__ void k_split4(const float* __restrict__ x, u16* __restrict__ ph,
                         u16* __restrict__ pl, int n4) {
  int i = blockIdx.x * 256 + threadIdx.x;
  if (i >= n4) return;
  float4 v = ((const float4*)x)[i];
  short4_t h4, l4;
  float vv[4] = {v.x, v.y, v.z, v.w};
#pragma unroll
  for (int q = 0; q < 4; ++q) {
    float f = RELU ? fmaxf(vv[q], 0.f) : vv[q];
    u16 h = f2bf(f);
    h4[q] = (short)h;
    if (LO) l4[q] = (short)f2bf(f - bf2f(h));
  }
  *(short4_t*)(ph + (size_t)i * 4) = h4;
  if (LO) *(short4_t*)(pl + (size_t)i * 4) = l4;
}

__global__ void k_xcat(const u16* __restrict__ f0, const u16* __restrict__ f1,
                       const u16* __restrict__ f2, const u16* __restrict__ f3,
                       const u16* __restrict__ f4, const int* __restrict__ ni1,
                       const int* __restrict__ ni2, u16* __restrict__ xcat, int b0) {
  const int G = 1280 / 8;
  int i = blockIdx.x * 256 + threadIdx.x;
  if (i >= 4 * NP0 * G) return;
  const int g = i % G, n = (i / G) % NP0, bl = i / (G * NP0);
  const int b = b0 + bl;
  const int k = g * 8;
  short8_t v;
  if (k < 128)      v = *(const short8_t*)(f0 + ((size_t)b * NP0 + n) * 128 + k);
  else if (k < 256) v = *(const short8_t*)(f1 + ((size_t)b * NP0 + n) * 128 + (k - 128));
  else if (k < 512) v = *(const short8_t*)(f2 + ((size_t)b * NP1 + ni1[b * NP0 + n]) * 256 + (k - 256));
  else if (k < 768) v = *(const short8_t*)(f3 + ((size_t)b * NP1 + ni1[b * NP0 + n]) * 256 + (k - 512));
  else              v = *(const short8_t*)(f4 + ((size_t)b * NP2 + ni2[b * NP0 + n]) * 512 + (k - 768));
  *(short8_t*)(xcat + ((size_t)bl * NP0 + n) * 1280 + k) = v;
}

// ===========================================================================
// KNN — LDS-free, early-exit radix descent (exact set).
// ===========================================================================
template <int NCAND, int KSEL>
__global__ __launch_bounds__(256) void k_knn_radix(const float4* __restrict__ v4,
                                                   int Nq, int* __restrict__ outIdx) {
  const int b = blockIdx.y;
  const int wave = threadIdx.x >> 6, lane = threadIdx.x & 63;
  const int qi = blockIdx.x * 4 + wave;
  const float4* vb4 = v4 + (size_t)b * NP0;
  const float4 qp = vb4[qi];
  constexpr int CH = NCAND / 64;
  unsigned d[CH];
  unsigned x[32];
#pragma unroll
  for (int j = 0; j < 32; ++j) x[j] = 0u;
#pragma unroll
  for (int j = 0; j < CH; ++j) {
    const int m = lane + j * 64;
    const float4 cp = vb4[m];
    const float dx = cp.x - qp.x, dy = cp.y - qp.y, dz = cp.z - qp.z;
    const float dd = dx * dx + dy * dy + dz * dz;
    d[j] = __float_as_uint((m == qi) ? FLT_MAX : dd);
    x[j] = d[j];
  }
#pragma unroll
  for (int st = 0; st < 5; ++st) {
    const int s = 16 >> st;
    const unsigned ml = (s == 16) ? 0x0000FFFFu : (s == 8) ? 0x00FF00FFu
                      : (s == 4) ? 0x0F0F0F0Fu : (s == 2) ? 0x33333333u : 0x55555555u;
#pragma unroll
    for (int i = 0; i < 32; ++i) {
      if (i & s) continue;
      unsigned t = ((x[i] >> s) ^ x[i + s]) & ml;
      x[i + s] ^= t;
      x[i] ^= (t << s);
    }
  }
  unsigned active = (CH == 32) ? 0xFFFFFFFFu : ((1u << CH) - 1u);
  unsigned T = 0u;
  int kk = KSEL;
  int actcnt = NCAND;
  bool done = false;
#pragma unroll 1
  for (int bb = 30; bb >= 2; bb -= 2) {
    const unsigned mh = x[bb], mlo = x[bb - 1];
    const unsigned a00 = active & ~mh & ~mlo;
    const unsigned a01 = active & ~mh & mlo;
    const unsigned a10 = active & mh & ~mlo;
    unsigned pA = (unsigned)__popc(a00) | ((unsigned)__popc(a01) << 16);
    unsigned pB = (unsigned)__popc(a10);
#pragma unroll
    for (int off = 32; off; off >>= 1) {
      pA += __shfl_xor(pA, off);
      pB += __shfl_xor(pB, off);
    }
    const int C00 = (int)(pA & 0xFFFFu), C01 = (int)(pA >> 16), C10 = (int)pB;
    if (kk <= C00) {
      active = a00; actcnt = C00;
    } else if (kk <= C00 + C01) {
      kk -= C00; active = a01; actcnt = C01; T |= 1u << (bb - 1);
    } else if (kk <= C00 + C01 + C10) {
      kk -= C00 + C01; active = a10; actcnt = C10; T |= 1u << bb;
    } else {
      kk -= C00 + C01 + C10;
      active = active & mh & mlo;
      actcnt = actcnt - C00 - C01 - C10;
      T |= 3u << (bb - 1);
    }
    if (actcnt == kk) { done = true; break; }  // entire active set selected
  }
  if (!done) {
    const unsigned zn = active & ~x[0];
    int c0 = __popc(zn);
#pragma unroll
    for (int off = 32; off; off >>= 1) c0 += __shfl_xor(c0, off);
    if (kk <= c0) active = zn;
    else { active &= x[0]; T |= 1u; }
  }
  int* orow = outIdx + ((size_t)b * Nq + qi) * KSEL;
  const unsigned long long ltmask = (1ull << lane) - 1ull;
  int base = 0;
#pragma unroll
  for (int j = 0; j < CH; ++j) {
    const bool sel = d[j] < T;
    const unsigned long long bal = __ballot(sel);
    const int pos = base + (int)__popcll(bal & ltmask);
    if (sel) orow[pos] = lane + j * 64;
    base += (int)__popcll(bal);
  }
  for (int j = 0; j < CH; ++j) {
    if (base >= KSEL) break;
    const bool sel = ((active >> j) & 1u) != 0u;
    const unsigned long long bal = __ballot(sel);
    const int pos = base + (int)__popcll(bal & ltmask);
    if (sel && pos < KSEL) orow[pos] = lane + j * 64;
    base += (int)__popcll(bal);
  }
}

template <int NCAND, int KSEL>
__global__ __launch_bounds__(256) void k_knn2(const float4* __restrict__ v4,
                                              int Nq, int* __restrict__ outIdx) {
  const int b = blockIdx.y;
  const int wave = threadIdx.x >> 6, lane = threadIdx.x & 63;
  const int qi = blockIdx.x * 4 + wave;
  const float4* vb4 = v4 + (size_t)b * NP0;
  const float4 qp = vb4[qi];
  constexpr int CH = NCAND / 64;
  float d[CH];
#pragma unroll
  for (int j = 0; j < CH; ++j) {
    const int m = lane + j * 64;
    const float4 cp = vb4[m];
    const float dx = cp.x - qp.x, dy = cp.y - qp.y, dz = cp.z - qp.z;
    const float dd = dx * dx + dy * dy + dz * dz;
    d[j] = (m == qi) ? FLT_MAX : dd;
  }
  int* orow = outIdx + ((size_t)b * Nq + qi) * KSEL;
#pragma unroll 1
  for (int s = 0; s < KSEL; ++s) {
    float bd = FLT_MAX; int bj = 0;
#pragma unroll
    for (int j = 0; j < CH; ++j) {
      const bool better = d[j] < bd;
      bd = better ? d[j] : bd;
      bj = better ? j : bj;
    }
    int bm = lane + bj * 64;
#pragma unroll
    for (int off = 32; off; off >>= 1) {
      const float od = __shfl_xor(bd, off);
      const int om = __shfl_xor(bm, off);
      if (od < bd || (od == bd && om < bm)) { bd = od; bm = om; }
    }
    if (lane == 0) orow[s] = bm;
#pragma unroll
    for (int j = 0; j < CH; ++j)
      if (bm == lane + j * 64) d[j] = FLT_MAX;
  }
}

__global__ void k_transpose(const float* __restrict__ in, float* __restrict__ out,
                            float* __restrict__ out4) {
  int i = blockIdx.x * 256 + threadIdx.x;
  if (i >= BB * NP0 * 3) return;
  int dd = i % 3, tt = (i / 3) % NP0, b = i / (3 * NP0);
  float v = in[((size_t)b * 3 + dd) * NP0 + tt];
  out[i] = v;
  out4[((size_t)b * NP0 + tt) * 4 + dd] = v;
}

// Vectorized conv: each thread owns 4 consecutive channels (float4 loads).
// TPP = C/4 threads per point; 256/TPP points per block. Bit-identical math.
template <int TPP>
__global__ __launch_bounds__(256) void k_conv_surface(
    const float* __restrict__ v, const int* __restrict__ idx,
    const float* __restrict__ dirs, float* __restrict__ out, int N, int M) {
  constexpr int PPB = 256 / TPP;
  __shared__ float su[PPB][KNB_ * 3];
  int b = blockIdx.y, t = threadIdx.x;
  const int p = t / TPP, l = t - p * TPP;
  const int n = blockIdx.x * PPB + p;
  const float* vb = v + (size_t)b * VS0;
  const float cx = vb[n * 3], cy = vb[n * 3 + 1], cz = vb[n * 3 + 2];
  const int* irow = idx + ((size_t)b * N + n) * KNB_;
  for (int kk = l; kk < KNB_; kk += TPP) {
    int j = irow[kk];
    float dx = vb[j * 3] - cx, dy = vb[j * 3 + 1] - cy, dz = vb[j * 3 + 2] - cz;
    float inv = 1.f / fmaxf(sqrtf(dx * dx + dy * dy + dz * dz), 1e-12f);
    su[p][kk * 3] = dx * inv; su[p][kk * 3 + 1] = dy * inv; su[p][kk * 3 + 2] = dz * inv;
  }
  __syncthreads();
  const int c4 = l * 4;
  float d0[4], d1[4], d2[4];
#pragma unroll
  for (int j = 0; j < 4; ++j) {
    float a = dirs[c4 + j], bq = dirs[M + c4 + j], cq = dirs[2 * M + c4 + j];
    float inv = 1.f / fmaxf(sqrtf(a * a + bq * bq + cq * cq), 1e-12f);
    d0[j] = a * inv; d1[j] = bq * inv; d2[j] = cq * inv;
  }
  float acc[4] = {0.f, 0.f, 0.f, 0.f};
  for (int k = 0; k < KNB_; ++k) {
    const float s0 = su[p][k * 3], s1 = su[p][k * 3 + 1], s2 = su[p][k * 3 + 2];
#pragma unroll
    for (int j = 0; j < 4; ++j) {
      float th = fmaxf(s0 * d0[j] + s1 * d1[j] + s2 * d2[j], 0.f);
      acc[j] = fmaxf(acc[j], th);
    }
  }
  float4 o = {acc[0], acc[1], acc[2], acc[3]};
  *(float4*)(out + ((size_t)b * N + n) * M + c4) = o;
}

template <int TPP>
__global__ __launch_bounds__(256) void k_conv_layer(
    const float* __restrict__ v, const int* __restrict__ idx,
    const float* __restrict__ dirs, const float* __restrict__ fout,
    float* __restrict__ out, int N, int C) {
  constexpr int PPB = 256 / TPP;
  __shared__ float su[PPB][KNB_ * 3];
  __shared__ int sidx[PPB][KNB_];
  int b = blockIdx.y, t = threadIdx.x;
  const int p = t / TPP, l = t - p * TPP;
  const int n = blockIdx.x * PPB + p;
  const float* vb = v + (size_t)b * VS0;
  const float cx = vb[n * 3], cy = vb[n * 3 + 1], cz = vb[n * 3 + 2];
  const int* irow = idx + ((size_t)b * N + n) * KNB_;
  for (int kk = l; kk < KNB_; kk += TPP) {
    int j = irow[kk]; sidx[p][kk] = j;
    float dx = vb[j * 3] - cx, dy = vb[j * 3 + 1] - cy, dz = vb[j * 3 + 2] - cz;
    float inv = 1.f / fmaxf(sqrtf(dx * dx + dy * dy + dz * dz), 1e-12f);
    su[p][kk * 3] = dx * inv; su[p][kk * 3 + 1] = dy * inv; su[p][kk * 3 + 2] = dz * inv;
  }
  __syncthreads();
  const int c4 = l * 4;
  float d0[4], d1[4], d2[4];
#pragma unroll
  for (int j = 0; j < 4; ++j) {
    float a = dirs[c4 + j], bq = dirs[C + c4 + j], cq = dirs[2 * C + c4 + j];
    float inv = 1.f / fmaxf(sqrtf(a * a + bq * bq + cq * cq), 1e-12f);
    d0[j] = a * inv; d1[j] = bq * inv; d2[j] = cq * inv;
  }
  const float* fb = fout + (size_t)b * N * 2 * C;
  float acc[4] = {-FLT_MAX, -FLT_MAX, -FLT_MAX, -FLT_MAX};
  for (int k = 0; k < KNB_; ++k) {
    const float s0 = su[p][k * 3], s1 = su[p][k * 3 + 1], s2 = su[p][k * 3 + 2];
    const float4 fs = *(const float4*)(fb + (size_t)sidx[p][k] * 2 * C + C + c4);
    const float fsv[4] = {fs.x, fs.y, fs.z, fs.w};
#pragma unroll
    for (int j = 0; j < 4; ++j) {
      float th = fmaxf(s0 * d0[j] + s1 * d1[j] + s2 * d2[j], 0.f);
      acc[j] = fmaxf(acc[j], th * fsv[j]);
    }
  }
  const float4 fc = *(const float4*)(fb + (size_t)n * 2 * C + c4);
  float4 o = {fc.x + acc[0], fc.y + acc[1], fc.z + acc[2], fc.w + acc[3]};
  *(float4*)(out + ((size_t)b * N + n) * C + c4) = o;
}

// ===========================================================================
// BN / pool / misc
// ===========================================================================
__global__ void k_bn_part(const float* __restrict__ x, int rows, int C, float* __restrict__ part) {
  const int blk = blockIdx.x;
  const int chunk = rows / 256;
  const int r0 = blk * chunk;
  const int c0 = threadIdx.x, c1 = threadIdx.x + 256;
  float s0 = 0, s20 = 0, s1 = 0, s21 = 0;
  for (int r = 0; r < chunk; ++r) {
    const float* row = x + (size_t)(r0 + r) * C;
    if (c0 < C) { float v = row[c0]; s0 += v; s20 += v * v; }
    if (c1 < C) { float v = row[c1]; s1 += v; s21 += v * v; }
  }
  float* p = part + (size_t)blk * 1024;
  if (c0 < C) { p[c0] = s0; p[512 + c0] = s20; }
  if (c1 < C) { p[c1] = s1; p[512 + c1] = s21; }
}

__global__ void k_bn_fin(const float* __restrict__ part, int rows, int C, float* __restrict__ stats) {
  __shared__ float sm0[8][32], sm1[8][32];
  const int cl = threadIdx.x & 31, ch = threadIdx.x >> 5;
  const int c = blockIdx.x * 32 + cl;
  float s = 0, s2 = 0;
  if (c < C) {
    for (int b2 = ch * 32; b2 < ch * 32 + 32; ++b2) {
      s += part[b2 * 1024 + c];
      s2 += part[b2 * 1024 + 512 + c];
    }
  }
  sm0[ch][cl] = s; sm1[ch][cl] = s2;
  __syncthreads();
  if (ch == 0 && c < C) {
    float S = 0, S2 = 0;
#pragma unroll
    for (int k = 0; k < 8; ++k) { S += sm0[k][cl]; S2 += sm1[k][cl]; }
    float m = S / rows;
    float var = S2 / rows - m * m;
    stats[c] = m;
    stats[C + c] = rsqrtf(var + 1e-5f);
  }
}

template <bool ADD>
__global__ void k_bn_apply(const float* __restrict__ x, const float* __restrict__ stats,
                           const float* __restrict__ g, const float* __restrict__ bb,
                           const float* __restrict__ base, float* __restrict__ outf,
                           u16* __restrict__ ph, u16* __restrict__ pl, int total, int C) {
  int i = blockIdx.x * 256 + threadIdx.x;
  if (i >= total) return;
  int c = i % C;
  float v = (x[i] - stats[c]) * stats[C + c] * g[c] + bb[c];
  v = fmaxf(v, 0.f);
  float r = ADD ? base[i] + v : v;
  outf[i] = r;
  u16 h = f2bf(r);
  ph[i] = h;
  pl[i] = f2bf(r - bf2f(h));
}

__global__ void k_pool(const u16* __restrict__ fh, const u16* __restrict__ fl,
                       const int* __restrict__ idxp, u16* __restrict__ oh,
                       u16* __restrict__ ol, int Nin, int pn, int C) {
  int b = blockIdx.y, p = blockIdx.x, c = threadIdx.x;
  const int* ir = idxp + ((size_t)b * pn + p) * 4;
  const u16* fhb = fh + (size_t)b * Nin * C;
  const u16* flb = fl + (size_t)b * Nin * C;
  float acc = -FLT_MAX;
#pragma unroll
  for (int k = 0; k < 4; ++k) {
    size_t o = (size_t)ir[k] * C + c;
    acc = fmaxf(acc, bf2f(fhb[o]) + bf2f(flb[o]));
  }
  u16 h = f2bf(acc);
  oh[((size_t)b * pn + p) * C + c] = h;
  ol[((size_t)b * pn + p) * C + c] = f2bf(acc - bf2f(h));
}

__global__ void k_maxn(const u16* __restrict__ fh, const u16* __restrict__ fl,
                       float* __restrict__ out, int N, int C) {
  int b = blockIdx.y;
  int c = blockIdx.x * 256 + threadIdx.x;
  if (c >= C) return;
  float acc = -FLT_MAX;
  for (int n = 0; n < N; ++n) {
    size_t o = ((size_t)b * N + n) * C + c;
    acc = fmaxf(acc, bf2f(fh[o]) + bf2f(fl[o]));
  }
  out[(size_t)b * C + c] = acc;
}

__global__ void k_nearest(const float* __restrict__ v, int Ns, int* __restrict__ out) {
  extern __shared__ float sp[];
  int b = blockIdx.y;
  const float* vsb = v + (size_t)b * VS0;
  for (int i = threadIdx.x; i < Ns * 3; i += 256) sp[i] = vsb[i];
  __syncthreads();
  int t = blockIdx.x * 256 + threadIdx.x;
  float tx = vsb[t * 3], ty = vsb[t * 3 + 1], tz = vsb[t * 3 + 2];
  float bd = FLT_MAX; int bi = 0;
#pragma unroll 4
  for (int s = 0; s < Ns; ++s) {
    float dx = sp[s * 3] - tx, dy = sp[s * 3 + 1] - ty, dz = sp[s * 3 + 2] - tz;
    float dd = dx * dx + dy * dy + dz * dz;
    if (dd < bd) { bd = dd; bi = s; }
  }
  out[(size_t)b * NP0 + t] = bi;
}

__global__ void k_glob1(const float* __restrict__ fglob, const float* __restrict__ onehot,
                        const float* __restrict__ h1w, const float* __restrict__ h1b,
                        float* __restrict__ out) {
  int b = blockIdx.x, j = threadIdx.x;
  float s = h1b[j];
  for (int i = 0; i < 512; ++i) s = fmaf(fglob[b * 512 + i], h1w[(size_t)(1280 + i) * 512 + j], s);
  for (int i = 0; i < 16; ++i) s = fmaf(onehot[b * 16 + i], h1w[(size_t)(1792 + i) * 512 + j], s);
  out[b * 512 + j] = s;
}

__global__ void k_logsoftmax(float* __restrict__ x, int rows, int C) {
  int r = blockIdx.x * 4 + (threadIdx.x >> 6);
  int lane = threadIdx.x & 63;
  if (r >= rows) return;
  float* xr = x + (size_t)r * C;
  float v = (lane < C) ? xr[lane] : -FLT_MAX;
  float mx = v;
  for (int o = 32; o; o >>= 1) mx = fmaxf(mx, __shfl_xor(mx, o));
  float e = (lane < C) ? __expf(v - mx) : 0.f;
  float s = e;
  for (int o = 32; o; o >>= 1) s += __shfl_xor(s, o);
  float lse = mx + logf(s);
  if (lane < C) xr[lane] = v - lse;
}

// ===========================================================================
// host
// ===========================================================================
struct Ws {
  float *v0, *v4, *fglob, *glob1, *mx, *inv, *csump, *stats, *bpart, *xcur, *pre, *fout, *xrp, *spart;
  int *idx0, *idxp0, *idx1, *idxp1, *idx2, *ni1, *ni2;
  u16 *wh, *wl;
  u16 *fm0h, *fm0l, *fm1h, *fm1l, *fm2h, *fm2l, *fm3h, *fm3l, *fm4h, *fm4l;
  u16 *fmp1h, *fmp1l, *fmp2h, *fmp2l, *qh, *ql, *vmh, *vml, *xsh, *xsl;
  u16 *x1h, *x2b, *xcat;
};

static void run_sa(hipStream_t st, Ws& ws, int N, int C, int Q,
                   const u16* qkvh, const u16* qkvl, const u16* twh, const u16* twl,
                   const float* vb, const float* tb, const float* g, const float* be,
                   u16* xh, u16* xl) {
  const long sx = (long)N * C;
  mmp<64, 0, 0, 4, false, false>(st, xh, xl, qkvh, qkvl, vb, ws.qh, ws.ql,
                                 N, Q + C, C, sx, 0, (long)N * Q, BB, 1,
                                 nullptr, 0, ws.vmh, ws.vml, Q, sx);
  if (Q == 32) {        // N=2048: stats NS=4, xr NSPLIT=2
    float* Sp = ws.spart + (size_t)4 * BB * N;
    k_sa_stats<32, 4><<<dim3(N / 64, BB, 4), 256, 0, st>>>(ws.qh, ws.ql, N,
        nullptr, nullptr, ws.spart, Sp);
    k_smerge<4><<<(BB * N + 255) / 256, 256, 0, st>>>(ws.spart, Sp, ws.mx, ws.inv, BB * N);
    dim3 gx(N / 64, C / 128, BB * 2);
    k_sa_xr<32, 2><<<gx, 256, 0, st>>>(ws.qh, ws.ql, ws.vmh, ws.vml, ws.mx, ws.inv,
                                       nullptr, nullptr, nullptr, ws.xrp, ws.csump, N, C);
    k_xsub2<2><<<((size_t)BB * N * C + 255) / 256, 256, 0, st>>>(
        ws.xrp, ws.csump, ws.xcur, ws.xsh, ws.xsl, N, C);
  } else if (Q == 64) { // N=512: stats NS=4, xr NSPLIT=4
    float* Sp = ws.spart + (size_t)4 * BB * N;
    k_sa_stats<64, 4><<<dim3(N / 64, BB, 4), 256, 0, st>>>(ws.qh, ws.ql, N,
        nullptr, nullptr, ws.spart, Sp);
    k_smerge<4><<<(BB * N + 255) / 256, 256, 0, st>>>(ws.spart, Sp, ws.mx, ws.inv, BB * N);
    dim3 gx(N / 64, C / 128, BB * 4);
    k_sa_xr<64, 4><<<gx, 256, 0, st>>>(ws.qh, ws.ql, ws.vmh, ws.vml, ws.mx, ws.inv,
                                       nullptr, nullptr, nullptr, ws.xrp, ws.csump, N, C);
    k_xsub2<4><<<((size_t)BB * N * C + 255) / 256, 256, 0, st>>>(
        ws.xrp, ws.csump, ws.xcur, ws.xsh, ws.xsl, N, C);
  } else {              // N=128: no split
    k_sa_stats<128, 1><<<dim3(N / 64, BB, 1), 256, 0, st>>>(ws.qh, ws.ql, N,
        ws.mx, ws.inv, nullptr, nullptr);
    dim3 gx(N / 64, C / 128, BB);
    k_sa_xr<128, 1><<<gx, 256, 0, st>>>(ws.qh, ws.ql, ws.vmh, ws.vml, ws.mx, ws.inv,
                                        ws.xcur, ws.xsh, ws.xsl, nullptr, nullptr, N, C);
  }
  mmp<64, 0, 1, 0, false, false>(st, ws.xsh, ws.xsl, twh, twl, tb, ws.pre, nullptr,
                                 N, C, C, sx, 0, sx, BB, 1);
  k_bn_part<<<256, 256, 0, st>>>(ws.pre, BB * N, C, ws.bpart);
  k_bn_fin<<<(C + 31) / 32, 256, 0, st>>>(ws.bpart, BB * N, C, ws.stats);
  k_bn_apply<true><<<(BB * N * C + 255) / 256, 256, 0, st>>>(ws.pre, ws.stats, g, be,
                                                             ws.xcur, ws.xcur, xh, xl, BB * N * C, C);
}

static void run_conv(hipStream_t st, Ws& ws, const u16* finh, const u16* finl, int Cin,
                     const u16* cwh, const u16* cwl, const float* bias, const float* dirs,
                     const int* idx, int N, int C,
                     const float* bng, const float* bnb, bool doBN, u16* fmh, u16* fml) {
  if (N == NP0)
    mmp<128, 0, 1, 0, false, false>(st, finh, finl, cwh, cwl, bias, ws.fout, nullptr,
                                    N, 2 * C, Cin, (long)N * Cin, 0, (long)N * 2 * C, BB, 1);
  else
    mmp<64, 0, 1, 0, false, false>(st, finh, finl, cwh, cwl, bias, ws.fout, nullptr,
                                   N, 2 * C, Cin, (long)N * Cin, 0, (long)N * 2 * C, BB, 1);
  if (C == 128)
    k_conv_layer<32><<<dim3(N / 8, BB), 256, 0, st>>>(ws.v0, idx, dirs, ws.fout, ws.xcur, N, C);
  else if (C == 256)
    k_conv_layer<64><<<dim3(N / 4, BB), 256, 0, st>>>(ws.v0, idx, dirs, ws.fout, ws.xcur, N, C);
  else
    k_conv_layer<128><<<dim3(N / 2, BB), 256, 0, st>>>(ws.v0, idx, dirs, ws.fout, ws.xcur, N, C);
  if (doBN) {
    k_bn_part<<<256, 256, 0, st>>>(ws.xcur, BB * N, C, ws.bpart);
    k_bn_fin<<<(C + 31) / 32, 256, 0, st>>>(ws.bpart, BB * N, C, ws.stats);
    k_bn_apply<false><<<(BB * N * C + 255) / 256, 256, 0, st>>>(
        ws.xcur, ws.stats, bng, bnb, nullptr, ws.xcur, fmh, fml, BB * N * C, C);
  } else {
    k_split4<false, true><<<(BB * N * C / 4 + 255) / 256, 256, 0, st>>>(
        ws.xcur, fmh, fml, BB * N * C / 4);
  }
}

extern "C" void kernel_launch(void* const* d_in, const int* in_sizes, int n_in,
                              void* d_out, int out_size, void* d_ws, size_t ws_size,
                              hipStream_t stream) {
  auto in = [&](int i) { return (const float*)d_in[i]; };
  char* p = (char*)d_ws;
  Ws ws;
  ws.v0 = (float*)(p + O_V0);
  ws.v4 = (float*)(p + O_V4);
  ws.idx0 = (int*)(p + O_IDX0); ws.idxp0 = (int*)(p + O_IDXP0);
  ws.idx1 = (int*)(p + O_IDX1); ws.idxp1 = (int*)(p + O_IDXP1);
  ws.idx2 = (int*)(p + O_IDX2);
  ws.ni1 = (int*)(p + O_NI1); ws.ni2 = (int*)(p + O_NI2);
  ws.fglob = (float*)(p + O_FGLOB); ws.glob1 = (float*)(p + O_GLOB1);
  ws.mx = (float*)(p + O_COLS); ws.inv = (float*)(p + O_CPART);
  ws.csump = (float*)(p + O_CPART + 65536);
  ws.stats = (float*)(p + O_STATS); ws.bpart = (float*)(p + O_BPART);
  ws.xcur = (float*)(p + O_XCUR);
  ws.pre = (float*)(p + O_AREA);
  ws.fout = (float*)(p + O_AREA);
  ws.xrp = (float*)(p + O_AREA);
  ws.spart = (float*)(p + O_AREA);
  ws.xcat = (u16*)(p + O_AREA);
  char* pl = p + O_PL;
  ws.wh = (u16*)(pl + PL_WH); ws.wl = (u16*)(pl + PL_WL);
  ws.fm0h = (u16*)(pl + PL_FM0H); ws.fm0l = (u16*)(pl + PL_FM0L);
  ws.fm1h = (u16*)(pl + PL_FM1H); ws.fm1l = (u16*)(pl + PL_FM1L);
  ws.fm2h = (u16*)(pl + PL_FM2H); ws.fm2l = (u16*)(pl + PL_FM2L);
  ws.fm3h = (u16*)(pl + PL_FM3H); ws.fm3l = (u16*)(pl + PL_FM3L);
  ws.fm4h = (u16*)(pl + PL_FM4H); ws.fm4l = (u16*)(pl + PL_FM4L);
  ws.fmp1h = (u16*)(pl + PL_FMP1H); ws.fmp1l = (u16*)(pl + PL_FMP1L);
  ws.fmp2h = (u16*)(pl + PL_FMP2H); ws.fmp2l = (u16*)(pl + PL_FMP2L);
  ws.qh = (u16*)(pl + PL_QH); ws.ql = (u16*)(pl + PL_QL);
  ws.vmh = (u16*)(pl + PL_VMH); ws.vml = (u16*)(pl + PL_VML);
  ws.xsh = (u16*)(pl + PL_XSH); ws.xsl = (u16*)(pl + PL_XSL);
  ws.x1h = (u16*)(pl + PL_X1H);
  ws.x2b = (u16*)(p + O_XCUR);
  float* out = (float*)d_out;

  // ---- one-time weight plane split (pre-transposed to [N,K]) ----
  SplitJobs jobs;
  size_t wq[22];
  size_t off = 0;
  int ji = 0;
  auto addjob = [&](const float* s, int K, int N, int trans) {
    int n = K * N;
    jobs.j[ji] = {s, ws.wh + off, ws.wl + off, n, K, N, trans};
    wq[ji] = off; off += (size_t)n; ++ji;
  };
  addjob(in(5), 128, 32, 0);  addjob(in(6), 128, 128, 0);  addjob(in(8), 128, 128, 0);
  addjob(in(17), 128, 32, 0); addjob(in(18), 128, 128, 0); addjob(in(20), 128, 128, 0);
  addjob(in(29), 256, 64, 0); addjob(in(30), 256, 256, 0); addjob(in(32), 256, 256, 0);
  addjob(in(41), 256, 64, 0); addjob(in(42), 256, 256, 0); addjob(in(44), 256, 256, 0);
  addjob(in(51), 512, 128, 0); addjob(in(52), 512, 512, 0); addjob(in(54), 512, 512, 0);
  addjob(in(12), 128, 256, 1);   // conv1
  addjob(in(24), 128, 512, 1);   // conv2
  addjob(in(36), 256, 512, 1);   // conv3
  addjob(in(48), 256, 1024, 1);  // conv4
  addjob(in(58), 1280, 512, 1);  // h1 combined [512][1280]
  addjob(in(60), 512, 512, 1);   // h2
  addjob(in(62), 512, 50, 1);    // h3
  k_splitjobs<<<dim3(32, 22), 256, 0, stream>>>(jobs);
  auto W = [&](int i) { return ws.wh + wq[i]; };
  auto Wl = [&](int i) { return ws.wl + wq[i]; };

  // ---- geometry ----
  k_transpose<<<(BB * NP0 * 3 + 255) / 256, 256, 0, stream>>>(in(0), ws.v0, ws.v4);
  k_knn_radix<NP0, KNB_><<<dim3(NP0 / 4, BB), 256, 0, stream>>>(
      (const float4*)ws.v4, NP0, ws.idx0);

  // ---- conv0 + bn0 ----
  k_conv_surface<32><<<dim3(NP0 / 8, BB), 256, 0, stream>>>(ws.v0, ws.idx0, in(2), ws.xcur, NP0, 128);
  k_bn_part<<<256, 256, 0, stream>>>(ws.xcur, BB * NP0, 128, ws.bpart);
  k_bn_fin<<<4, 256, 0, stream>>>(ws.bpart, BB * NP0, 128, ws.stats);
  k_bn_apply<false><<<(BB * NP0 * 128 + 255) / 256, 256, 0, stream>>>(
      ws.xcur, ws.stats, in(3), in(4), nullptr, ws.xcur, ws.fm0h, ws.fm0l, BB * NP0 * 128, 128);

  // ---- sa0, conv1+bn1, sa1 ----
  run_sa(stream, ws, NP0, 128, 32, W(0), Wl(0), W(2), Wl(2),
         in(7), in(9), in(10), in(11), ws.fm0h, ws.fm0l);
  run_conv(stream, ws, ws.fm0h, ws.fm0l, 128, W(15), Wl(15), in(13), in(14), ws.idx0,
           NP0, 128, in(15), in(16), true, ws.fm1h, ws.fm1l);
  run_sa(stream, ws, NP0, 128, 32, W(3), Wl(3), W(5), Wl(5),
         in(19), in(21), in(22), in(23), ws.fm1h, ws.fm1l);

  // ---- pool1, knn1 ----
  k_knn2<NP0, 4><<<dim3(NP1 / 4, BB), 256, 0, stream>>>((const float4*)ws.v4, NP1, ws.idxp0);
  k_pool<<<dim3(NP1, BB), 128, 0, stream>>>(ws.fm1h, ws.fm1l, ws.idxp0,
                                            ws.fmp1h, ws.fmp1l, NP0, NP1, 128);
  k_knn_radix<NP1, KNB_><<<dim3(NP1 / 4, BB), 256, 0, stream>>>(
      (const float4*)ws.v4, NP1, ws.idx1);

  // ---- conv2+bn2, sa2, conv3+bn3, sa3 ----
  run_conv(stream, ws, ws.fmp1h, ws.fmp1l, 128, W(16), Wl(16), in(25), in(26), ws.idx1,
           NP1, 256, in(27), in(28), true, ws.fm2h, ws.fm2l);
  run_sa(stream, ws, NP1, 256, 64, W(6), Wl(6), W(8), Wl(8),
         in(31), in(33), in(34), in(35), ws.fm2h, ws.fm2l);
  run_conv(stream, ws, ws.fm2h, ws.fm2l, 256, W(17), Wl(17), in(37), in(38), ws.idx1,
           NP1, 256, in(39), in(40), true, ws.fm3h, ws.fm3l);
  run_sa(stream, ws, NP1, 256, 64, W(9), Wl(9), W(11), Wl(11),
         in(43), in(45), in(46), in(47), ws.fm3h, ws.fm3l);

  // ---- pool2, knn2, conv4 (no bn), sa4 ----
  k_knn2<NP1, 4><<<dim3(NP2 / 4, BB), 256, 0, stream>>>((const float4*)ws.v4, NP2, ws.idxp1);
  k_pool<<<dim3(NP2, BB), 256, 0, stream>>>(ws.fm3h, ws.fm3l, ws.idxp1,
                                            ws.fmp2h, ws.fmp2l, NP1, NP2, 256);
  k_knn_radix<NP2, KNB_><<<dim3(NP2 / 4, BB), 256, 0, stream>>>(
      (const float4*)ws.v4, NP2, ws.idx2);
  run_conv(stream, ws, ws.fmp2h, ws.fmp2l, 256, W(18), Wl(18), in(49), in(50), ws.idx2,
           NP2, 512, nullptr, nullptr, false, ws.fm4h, ws.fm4l);
  run_sa(stream, ws, NP2, 512, 128, W(12), Wl(12), W(14), Wl(14),
         in(53), in(55), in(56), in(57), ws.fm4h, ws.fm4l);

  // ---- global max, nearest, head ----
  k_maxn<<<dim3(2, BB), 256, 0, stream>>>(ws.fm4h, ws.fm4l, ws.fglob, NP2, 512);
  k_nearest<<<dim3(NP0 / 256, BB), 256, NP1 * 3 * 4, stream>>>(ws.v0, NP1, ws.ni1);
  k_nearest<<<dim3(NP0 / 256, BB), 256, NP2 * 3 * 4, stream>>>(ws.v0, NP2, ws.ni2);
  k_glob1<<<BB, 512, 0, stream>>>(ws.fglob, in(1), in(58), in(59), ws.glob1);

  for (int hf = 0; hf < 2; ++hf) {
    const int b0 = hf * 4;
    k_xcat<<<(4 * NP0 * 160 + 255) / 256, 256, 0, stream>>>(
        ws.fm0h, ws.fm1h, ws.fm2h, ws.fm3h, ws.fm4h, ws.ni1, ws.ni2, ws.xcat, b0);
    mmp<128, 2, 2, 3, false, false, false>(stream, ws.xcat, nullptr, W(19), nullptr,
        ws.glob1 + b0 * 512, ws.x1h, nullptr,
        NP0, 512, 1280, (long)NP0 * 1280, 0, (long)NP0 * 512, 4, 1);
    mmp<128, 2, 1, 3, false, false, false>(stream, ws.x1h, nullptr, W(20), nullptr, in(61),
        ws.x2b, nullptr, NP0, 512, 512, (long)NP0 * 512, 0, (long)NP0 * 512, 4, 1);
    mmp<64, 2, 1, 0, false, false, false>(stream, ws.x2b, nullptr, W(21), nullptr, in(63),
        out + (size_t)b0 * NP0 * 50, nullptr, NP0, 50, 512,
        (long)NP0 * 512, 0, (long)NP0 * 50, 4, 1);
  }

  k_logsoftmax<<<(BB * NP0) / 4, 256, 0, stream>>>(out, BB * NP0, 50);
}